// Round 10
// baseline (582.095 us; speedup 1.0000x reference)
//
#include <hip/hip_runtime.h>
#include <hip/hip_bf16.h>
#include <cstdint>
#include <math.h>

// SEDformer block: BN-folded bf16 MFMA GEMMs + in-place chunked EMA scan + RFF linear attention.
// L=2048 BS=16 D=512 H=8 DH=64 R=48 HID=2048; rows NR = L*BS = 32768.
// R10: attention TLP — register-dieted attn_A/B (<=128 VGPR, launch_bounds(512,4)),
// one c-tile per wave, grid (128,4) = 2 blocks/CU, phiQ sliced to [16][72].

typedef float  f32x4 __attribute__((ext_vector_type(4)));
typedef short  s16x8 __attribute__((ext_vector_type(8)));
typedef unsigned short u16x4 __attribute__((ext_vector_type(4)));

#define DEV static __device__ __forceinline__

constexpr int NR = 32768;          // L*BS

DEV float us2f(unsigned short u) {
  union { unsigned int i; float f; } z; z.i = ((unsigned int)u) << 16; return z.f;
}
DEV unsigned short f2bits(float f) {          // RNE f32 -> bf16 bits
  unsigned int u = __builtin_bit_cast(unsigned int, f);
  unsigned int r = u + 0x7fffu + ((u >> 16) & 1u);
  return (unsigned short)(r >> 16);
}

DEV void gload_lds16(const void* g, void* l) {
  __builtin_amdgcn_global_load_lds((__attribute__((address_space(1))) void*)g,
                                   (__attribute__((address_space(3))) void*)l, 16, 0, 0);
}

// ---------------- param prep: BN scale/shift + membrane betas + dot-acc zeroing ----------------
struct PrepArgs {
  const float *g[7], *b[7], *m[7], *v[7];   // bn1,bnq,bnk,bnv,bn2,bnf1,bnf2
  const float *wtq, *wtk;
  float *s[7], *t[7];
  float *betaq, *betak;
  float *dotqkv, *dot1;                     // 1536 / 2048, zeroed here
};

__global__ void prep_vectors(PrepArgs a) {
  int i = blockIdx.x * 256 + threadIdx.x;   // 0..2047
  const int dims[7] = {512, 512, 512, 512, 512, 2048, 512};
  #pragma unroll
  for (int k = 0; k < 7; ++k) {
    if (i < dims[k]) {
      float sc = a.g[k][i] * rsqrtf(a.v[k][i] + 1e-5f);
      a.s[k][i] = sc;
      a.t[k][i] = a.b[k][i] - a.m[k][i] * sc;
    }
  }
  if (i < 1536) a.dotqkv[i] = 0.f;
  if (i < 2048) a.dot1[i] = 0.f;
  if (i < 512) {
    float w = a.wtq[i];
    float sp = (w > 20.f) ? w : log1pf(expf(w));
    float be = 1.f - 1.f / (sp + 1.f);
    a.betaq[i] = fminf(fmaxf(be, 0.f), 0.9999f);
    w = a.wtk[i];
    sp = (w > 20.f) ? w : log1pf(expf(w));
    be = 1.f - 1.f / (sp + 1.f);
    a.betak[i] = fminf(fmaxf(be, 0.f), 0.9999f);
  }
}

// -------- coalesced fold: 64x64 LDS-transpose tile; W[K][Nn] -> WT bf16 [Nn][K] --------
__global__ void fold_wT2(const float* __restrict__ W, int K, int Nn,
                         const float* scin, const float* scout,
                         const float* tin, float* dotacc,
                         unsigned short* __restrict__ WT) {
  __shared__ float tile[64][65];
  __shared__ float dsum[4][64];
  const int j0 = blockIdx.x * 64, d0 = blockIdx.y * 64;
  const int tid = threadIdx.x;
  const int j = tid & 63, r = tid >> 6;
  float dpart = 0.f;
  #pragma unroll
  for (int i = 0; i < 16; ++i) {
    int dd = i * 4 + r;
    float w = W[(size_t)(d0 + dd) * Nn + j0 + j];
    tile[dd][j] = w;
    if (tin) dpart += tin[d0 + dd] * w;
  }
  if (tin) dsum[r][j] = dpart;
  __syncthreads();
  if (tin && r == 0)
    atomicAdd(&dotacc[j0 + j], dsum[0][j] + dsum[1][j] + dsum[2][j] + dsum[3][j]);
  const int d = j;
  const float si = scin ? scin[d0 + d] : 1.f;
  #pragma unroll
  for (int i = 0; i < 16; ++i) {
    int jj = i * 4 + r;
    float so = scout ? scout[j0 + jj] : 1.f;
    WT[(size_t)(j0 + jj) * K + d0 + d] = f2bits(tile[d][jj] * si * so);
  }
}

// -------- legacy per-column fold (kept for tiny rffW: K=64, N=48) --------
__global__ void fold_wT(const float* __restrict__ W, int K, int Nn,
                        unsigned short* __restrict__ WT) {
  int j = blockIdx.x;
  int lane = threadIdx.x;   // 64
  for (int dd = lane; dd < K; dd += 64)
    WT[(size_t)j * K + dd] = f2bits(W[(size_t)dd * Nn + j]);
}

// -------- bias finalize --------
struct BiasArgs {
  const float *dotqkv, *dot1, *bv, *fc1b, *fc2b;
  const float *s1, *t1, *s2, *t2, *s3, *t3, *s5, *t5, *s6, *t6;
  float *c_qkv, *c1, *c2;
};
__global__ void bias_fin(BiasArgs a) {
  int i = blockIdx.x * 256 + threadIdx.x;   // 0..2047
  if (i < 512) {
    a.c_qkv[i]        = a.s1[i] * a.dotqkv[i]        + a.t1[i];
    a.c_qkv[512 + i]  = a.s2[i] * a.dotqkv[512 + i]  + a.t2[i];
    a.c_qkv[1024 + i] = a.s3[i] * (a.dotqkv[1024 + i] + a.bv[i]) + a.t3[i];
    a.c2[i]           = a.s6[i] * a.fc2b[i] + a.t6[i];
  }
  if (i < 2048) a.c1[i] = a.s5[i] * (a.dot1[i] + a.fc1b[i]) + a.t5[i];
}

// ---------------- cast x f32 -> bf16 ----------------
__global__ void cast_x(const float* __restrict__ x, unsigned short* __restrict__ xb, int n) {
  int i = (blockIdx.x * blockDim.x + threadIdx.x) * 4;
  if (i >= n) return;
  float4 v = *(const float4*)(x + i);
  u16x4 o = {f2bits(v.x), f2bits(v.y), f2bits(v.z), f2bits(v.w)};
  *(u16x4*)(xb + i) = o;
}

// ---------------- GEMM: C[M,N] = A[M,K](bf16) * BT[N,K](bf16)^T + bias, fused epilogues --------
// MODE 0: outb = bf16(acc+bias)
// MODE 1: outb = bf16(us2f(xresb) + acc + bias)
// MODE 2: outb = bf16(gelu(acc+bias))   (sigmoid-form tanh gelu)
// MODE 3: outf = us2f(xresb) + acc + bias
template <int MODE>
__global__ __launch_bounds__(256, 4) void gemm_bf16(
    const unsigned short* __restrict__ A, const unsigned short* __restrict__ BT,
    int K, int Nn, const float* __restrict__ bias,
    const unsigned short* __restrict__ xresb,
    float* __restrict__ outf, unsigned short* __restrict__ outb) {
  __shared__ __align__(16) unsigned short Ab[2][128 * 32];
  __shared__ __align__(16) unsigned short Bb[2][128 * 32];
  const int tid = threadIdx.x, w = tid >> 6, lane = tid & 63;
  const int l15 = lane & 15, lg = lane >> 4;
  const int row0 = blockIdx.x * 128, col0 = blockIdx.y * 128;
  const int wr = w >> 1, wc = w & 1;
  const unsigned short* Abase = A + (size_t)row0 * K;
  const unsigned short* Bbase = BT + (size_t)col0 * K;

  auto stage = [&](int buf, int kt) {
    #pragma unroll
    for (int s = 0; s < 2; ++s) {
      int c = s * 256 + w * 64 + lane;
      gload_lds16(Abase + (size_t)(c >> 2) * K + kt * 32 + (c & 3) * 8,
                  &Ab[buf][(s * 256 + w * 64) * 8]);
      gload_lds16(Bbase + (size_t)(c >> 2) * K + kt * 32 + (c & 3) * 8,
                  &Bb[buf][(s * 256 + w * 64) * 8]);
    }
  };

  const f32x4 fz = {0.f, 0.f, 0.f, 0.f};
  f32x4 acc[4][4];
  #pragma unroll
  for (int m = 0; m < 4; ++m)
    #pragma unroll
    for (int n = 0; n < 4; ++n) acc[m][n] = fz;

  stage(0, 0);
  __syncthreads();
  int cur = 0;
  const int nt = K >> 5;
  for (int kt = 0; kt < nt; ++kt) {
    if (kt + 1 < nt) stage(cur ^ 1, kt + 1);
    s16x8 af[4], bf[4];
    #pragma unroll
    for (int m = 0; m < 4; ++m)
      af[m] = *(const s16x8*)&Ab[cur][(wr * 64 + m * 16 + l15) * 32 + lg * 8];
    #pragma unroll
    for (int n = 0; n < 4; ++n)
      bf[n] = *(const s16x8*)&Bb[cur][(wc * 64 + n * 16 + l15) * 32 + lg * 8];
    #pragma unroll
    for (int m = 0; m < 4; ++m)
      #pragma unroll
      for (int n = 0; n < 4; ++n)
        acc[m][n] = __builtin_amdgcn_mfma_f32_16x16x32_bf16(af[m], bf[n], acc[m][n], 0, 0, 0);
    __syncthreads();
    cur ^= 1;
  }

  #pragma unroll
  for (int m = 0; m < 4; ++m) {
    #pragma unroll
    for (int q = 0; q < 4; ++q) {
      int row = row0 + wr * 64 + m * 16 + lg * 4 + q;
      #pragma unroll
      for (int n = 0; n < 4; ++n) {
        int col = col0 + wc * 64 + n * 16 + l15;
        float v = acc[m][n][q] + bias[col];
        size_t idx = (size_t)row * Nn + col;
        if constexpr (MODE == 0) {
          outb[idx] = f2bits(v);
        } else if constexpr (MODE == 1) {
          outb[idx] = f2bits(us2f(xresb[idx]) + v);
        } else if constexpr (MODE == 2) {
          float u2 = v * 1.5957691216f * (1.f + 0.044715f * v * v);
          float gl = v / (1.f + __expf(-u2));
          outb[idx] = f2bits(gl);
        } else {
          outf[idx] = us2f(xresb[idx]) + v;
        }
      }
    }
  }
}

// ---------------- membrane EMA scan over L, IN-PLACE, coalesced, 8-wide batched ----------------
__global__ __launch_bounds__(1024) void mem_scan2(unsigned short* __restrict__ qkv,
                         const float* __restrict__ betaq, const float* __restrict__ betak) {
  __shared__ float carry[16][64];
  __shared__ float pre[16][64];
  int cg = blockIdx.x & 15, b = blockIdx.x >> 4;
  int w = threadIdx.x >> 6, lane = threadIdx.x & 63;
  int ch = cg * 64 + lane;
  const float beta = (ch < 512) ? betaq[ch] : betak[ch - 512];
  const float om = 1.f - beta;
  unsigned short* base = qkv + (size_t)b * 1536 + ch;
  const size_t rs = 16 * 1536;     // shorts per L-step
  const int l0 = w * 128;

  float m = 0.f;
  for (int i = 0; i < 128; i += 8) {
    float v[8];
    #pragma unroll
    for (int j = 0; j < 8; ++j) v[j] = us2f(base[(size_t)(l0 + i + j) * rs]);
    #pragma unroll
    for (int j = 0; j < 8; ++j) m = beta * m + om * v[j];
  }
  carry[w][lane] = m;
  __syncthreads();
  if (w == 0) {
    float pw = beta;
    #pragma unroll
    for (int t = 0; t < 7; ++t) pw *= pw;   // beta^128
    float run = 0.f;
    for (int cc = 0; cc < 16; ++cc) {
      pre[cc][lane] = run;
      run = carry[cc][lane] + pw * run;
    }
  }
  __syncthreads();
  m = pre[w][lane];
  for (int i = 0; i < 128; i += 8) {
    float v[8];
    #pragma unroll
    for (int j = 0; j < 8; ++j) v[j] = us2f(base[(size_t)(l0 + i + j) * rs]);
    #pragma unroll
    for (int j = 0; j < 8; ++j) {
      m = beta * m + om * v[j];
      base[(size_t)(l0 + i + j) * rs] = f2bits(m);
    }
  }
}

// ---------------- transpose v: qkv v-cols -> vT[b,h,dh][L] ----------------
__global__ void transpose_v(const unsigned short* __restrict__ qkv, unsigned short* __restrict__ vT) {
  __shared__ __align__(16) unsigned short tile[64][72];
  int bid = blockIdx.x;
  int lt = bid & 31, h = (bid >> 5) & 7, b = bid >> 8;
  int l0 = lt * 64;
  int tid = threadIdx.x;
  int r = tid >> 2, cg = (tid & 3) * 16;
  const unsigned short* src = qkv + (size_t)((l0 + r) * 16 + b) * 1536 + 1024 + h * 64 + cg;
  *(s16x8*)&tile[r][cg] = *(const s16x8*)(src);
  *(s16x8*)&tile[r][cg + 8] = *(const s16x8*)(src + 8);
  __syncthreads();
  int dh = tid >> 2, lgp = (tid & 3) * 16;
  s16x8 o0, o1;
  #pragma unroll
  for (int j = 0; j < 8; ++j) {
    o0[j] = (short)tile[lgp + j][dh];
    o1[j] = (short)tile[lgp + 8 + j][dh];
  }
  unsigned short* dstp = vT + (size_t)((b * 8 + h) * 64 + dh) * 2048 + l0 + lgp;
  *(s16x8*)dstp = o0;
  *(s16x8*)(dstp + 8) = o1;
}

// ---------------- RFF linear attention phase A: KV + Ksum partials ----------------
// grid (128 bh, 4 quarter), 512 thr (8 waves); each wave owns ONE 64-l tile (c = q*8+w).
// Register-dieted (<=128 VGPR target): per-m kf load, transient KV f32x4, LDS atomics.
__global__ __launch_bounds__(512, 4) void attn_A(
    const unsigned short* __restrict__ qkv, const unsigned short* __restrict__ vT,
    const unsigned short* __restrict__ WrT, const float* __restrict__ rffb,
    float* __restrict__ KVg, float* __restrict__ Ksumg) {
  __shared__ float KV[48][64];
  __shared__ float Ksum[48];
  __shared__ __align__(16) unsigned short phiT[8][48][72];

  const int tid = threadIdx.x;
  const int w = tid >> 6, lane = tid & 63, l15 = lane & 15, lg = lane >> 4;
  const int bh = blockIdx.x, b = bh >> 3, h = bh & 7;
  const int l0 = (blockIdx.y * 8 + w) * 64;
  const f32x4 fz = {0.f, 0.f, 0.f, 0.f};
  constexpr float ISR = 0.14433756729740643f;   // 1/sqrt(48)

  for (int i = tid; i < 48 * 64; i += 512) (&KV[0][0])[i] = 0.f;
  if (tid < 48) Ksum[tid] = 0.f;
  __syncthreads();

  s16x8 wf[3][2];
  float bias_n[3];
  #pragma unroll
  for (int n = 0; n < 3; ++n) {
    int r = n * 16 + l15;
    bias_n[n] = rffb[h * 48 + r];
    #pragma unroll
    for (int ks = 0; ks < 2; ++ks)
      wf[n][ks] = *(const s16x8*)(WrT + (size_t)(h * 48 + r) * 64 + ks * 32 + lg * 8);
  }

  // phi_k for this wave's 64-l tile
  f32x4 p[4][3];
  #pragma unroll
  for (int m = 0; m < 4; ++m) {
    size_t ro = (size_t)((l0 + m * 16 + l15) * 16 + b) * 1536 + 512 + h * 64;
    s16x8 kf0 = *(const s16x8*)(qkv + ro + lg * 8);
    s16x8 kf1 = *(const s16x8*)(qkv + ro + 32 + lg * 8);
    #pragma unroll
    for (int n = 0; n < 3; ++n) {
      p[m][n] = fz + bias_n[n];
      p[m][n] = __builtin_amdgcn_mfma_f32_16x16x32_bf16(kf0, wf[n][0], p[m][n], 0, 0, 0);
      p[m][n] = __builtin_amdgcn_mfma_f32_16x16x32_bf16(kf1, wf[n][1], p[m][n], 0, 0, 0);
    }
  }
  float ks_acc[3] = {0.f, 0.f, 0.f};
  #pragma unroll
  for (int m = 0; m < 4; ++m)
    #pragma unroll
    for (int n = 0; n < 3; ++n) {
      u16x4 pk;
      #pragma unroll
      for (int q = 0; q < 4; ++q) {
        float pv = p[m][n][q];
        float ph = (pv > 0.f ? pv + 1.000001f : __expf(pv) + 1e-6f) * ISR;
        ks_acc[n] += ph;
        pk[q] = f2bits(ph);
      }
      *(u16x4*)&phiT[w][n * 16 + l15][m * 16 + lg * 4] = pk;
    }
  #pragma unroll
  for (int n = 0; n < 3; ++n) {
    float t = ks_acc[n];
    t += __shfl_xor(t, 16);
    t += __shfl_xor(t, 32);
    if (lane < 16) atomicAdd(&Ksum[n * 16 + lane], t);
  }

  // KV += phi_k^T . v  (per (mm,nn) transient accumulator -> LDS atomics)
  const size_t vbase = (size_t)(b * 8 + h) * 64 * 2048;
  #pragma unroll
  for (int nn = 0; nn < 4; ++nn) {
    size_t vo = vbase + (size_t)(nn * 16 + l15) * 2048 + l0;
    s16x8 vf0 = *(const s16x8*)(vT + vo + lg * 8);
    s16x8 vf1 = *(const s16x8*)(vT + vo + 32 + lg * 8);
    #pragma unroll
    for (int mm = 0; mm < 3; ++mm) {
      s16x8 pf0 = *(const s16x8*)&phiT[w][mm * 16 + l15][lg * 8];
      s16x8 pf1 = *(const s16x8*)&phiT[w][mm * 16 + l15][32 + lg * 8];
      f32x4 a = fz;
      a = __builtin_amdgcn_mfma_f32_16x16x32_bf16(pf0, vf0, a, 0, 0, 0);
      a = __builtin_amdgcn_mfma_f32_16x16x32_bf16(pf1, vf1, a, 0, 0, 0);
      #pragma unroll
      for (int q = 0; q < 4; ++q)
        atomicAdd(&KV[mm * 16 + lg * 4 + q][nn * 16 + l15], a[q]);
    }
  }
  __syncthreads();

  float* dst = KVg + (size_t)(blockIdx.y * 128 + bh) * 3072;
  for (int i = tid; i < 48 * 64; i += 512) dst[i] = (&KV[0][0])[i];
  if (tid < 48) Ksumg[(blockIdx.y * 128 + bh) * 48 + tid] = Ksum[tid];
}

// ---------------- RFF linear attention phase B: phi_q, num/den, output ----------------
// grid (128,4), one 64-l tile per wave; phiQ sliced per-m to [8][16][72] (30KB LDS total).
__global__ __launch_bounds__(512, 4) void attn_B(
    const unsigned short* __restrict__ qkv, const unsigned short* __restrict__ WrT,
    const float* __restrict__ rffb, const float* __restrict__ KVg,
    const float* __restrict__ Ksumg, unsigned short* __restrict__ attn) {
  __shared__ __align__(16) unsigned short KVT[80][72];
  __shared__ __align__(16) unsigned short phiQ[8][16][72];

  const int tid = threadIdx.x;
  const int w = tid >> 6, lane = tid & 63, l15 = lane & 15, lg = lane >> 4;
  const int bh = blockIdx.x, b = bh >> 3, h = bh & 7;
  const int l0 = (blockIdx.y * 8 + w) * 64;
  const f32x4 fz = {0.f, 0.f, 0.f, 0.f};
  constexpr float ISR = 0.14433756729740643f;   // 1/sqrt(48)

  // zero pad cols 48..71 of this wave's slice (multiply zero KVT rows, but guard NaN bits)
  for (int i = lane; i < 16 * 24; i += 64) {
    int rr = i / 24, cc = 48 + i - (i / 24) * 24;
    phiQ[w][rr][cc] = 0;
  }
  // KVT = [sum of 4 partial KV slices | clip(sum Ksum)]^T, bf16, zero-padded
  for (int i = tid; i < 80 * 72; i += 512) {
    int dhe = i / 72, rr = i - dhe * 72;
    float val = 0.f;
    if (rr < 48) {
      if (dhe < 64) {
        val = KVg[(size_t)bh * 3072 + rr * 64 + dhe]
            + KVg[(size_t)(128 + bh) * 3072 + rr * 64 + dhe]
            + KVg[(size_t)(256 + bh) * 3072 + rr * 64 + dhe]
            + KVg[(size_t)(384 + bh) * 3072 + rr * 64 + dhe];
      } else if (dhe == 64) {
        val = fmaxf(Ksumg[bh * 48 + rr] + Ksumg[(128 + bh) * 48 + rr]
                  + Ksumg[(256 + bh) * 48 + rr] + Ksumg[(384 + bh) * 48 + rr], 1e-6f);
      }
    }
    (&KVT[0][0])[i] = f2bits(val);
  }
  __syncthreads();

  s16x8 wf[3][2];
  float bias_n[3];
  #pragma unroll
  for (int n = 0; n < 3; ++n) {
    int r = n * 16 + l15;
    bias_n[n] = rffb[h * 48 + r];
    #pragma unroll
    for (int ks = 0; ks < 2; ++ks)
      wf[n][ks] = *(const s16x8*)(WrT + (size_t)(h * 48 + r) * 64 + ks * 32 + lg * 8);
  }

  #pragma unroll
  for (int m = 0; m < 4; ++m) {
    size_t ro = (size_t)((l0 + m * 16 + l15) * 16 + b) * 1536 + h * 64;
    s16x8 qf0 = *(const s16x8*)(qkv + ro + lg * 8);
    s16x8 qf1 = *(const s16x8*)(qkv + ro + 32 + lg * 8);
    f32x4 pm[3];
    #pragma unroll
    for (int n = 0; n < 3; ++n) {
      pm[n] = fz + bias_n[n];
      pm[n] = __builtin_amdgcn_mfma_f32_16x16x32_bf16(qf0, wf[n][0], pm[n], 0, 0, 0);
      pm[n] = __builtin_amdgcn_mfma_f32_16x16x32_bf16(qf1, wf[n][1], pm[n], 0, 0, 0);
    }
    #pragma unroll
    for (int n = 0; n < 3; ++n)
      #pragma unroll
      for (int q = 0; q < 4; ++q) {
        float pv = pm[n][q];
        float ph = (pv > 0.f ? pv + 1.000001f : __expf(pv) + 1e-6f) * ISR;
        phiQ[w][lg * 4 + q][n * 16 + l15] = f2bits(ph);
      }
    s16x8 af0 = *(const s16x8*)&phiQ[w][l15][lg * 8];
    s16x8 af1 = *(const s16x8*)&phiQ[w][l15][32 + lg * 8];
    f32x4 o[5];
    #pragma unroll
    for (int n5 = 0; n5 < 5; ++n5) {
      s16x8 b0 = *(const s16x8*)&KVT[n5 * 16 + l15][lg * 8];
      s16x8 b1 = *(const s16x8*)&KVT[n5 * 16 + l15][32 + lg * 8];
      o[n5] = fz;
      o[n5] = __builtin_amdgcn_mfma_f32_16x16x32_bf16(af0, b0, o[n5], 0, 0, 0);
      o[n5] = __builtin_amdgcn_mfma_f32_16x16x32_bf16(af1, b1, o[n5], 0, 0, 0);
    }
    #pragma unroll
    for (int q = 0; q < 4; ++q) {
      float den = __shfl(o[4][q], lane & 48);
      float inv = 1.f / (den + 1e-6f);
      int gl = l0 + m * 16 + lg * 4 + q;
      size_t ob = (size_t)(gl * 16 + b) * 512 + h * 64;
      #pragma unroll
      for (int n = 0; n < 4; ++n)
        attn[ob + n * 16 + l15] = f2bits(o[n][q] * inv);
    }
  }
}

// ---------------- host ----------------
extern "C" void kernel_launch(void* const* d_in, const int* in_sizes, int n_in,
                              void* d_out, int out_size, void* d_ws, size_t ws_size,
                              hipStream_t stream) {
  (void)in_sizes; (void)n_in; (void)out_size; (void)ws_size;
  const float* x = (const float*)d_in[0];
  const float* Wq = (const float*)d_in[29];
  const float* Wk = (const float*)d_in[30];
  const float* Wv = (const float*)d_in[31];
  const float* bv = (const float*)d_in[32];
  const float* Wo = (const float*)d_in[33];
  const float* bo = (const float*)d_in[34];
  const float* wtq = (const float*)d_in[35];
  const float* wtk = (const float*)d_in[36];
  const float* rffW = (const float*)d_in[37];
  const float* rffb = (const float*)d_in[38];
  const float* fc1W = (const float*)d_in[39];
  const float* fc1b = (const float*)d_in[40];
  const float* fc2W = (const float*)d_in[41];
  const float* fc2b = (const float*)d_in[42];

  char* cur = (char*)d_ws;
  auto alloc = [&](size_t bytes) -> char* {
    char* r = cur;
    cur += (bytes + 255) & ~(size_t)255;
    return r;
  };
  float* sv_[7];
  float* tv_[7];
  const int dims[7] = {512, 512, 512, 512, 512, 2048, 512};
  for (int k = 0; k < 7; ++k) {
    sv_[k] = (float*)alloc(dims[k] * 4);
    tv_[k] = (float*)alloc(dims[k] * 4);
  }
  float* betaq = (float*)alloc(512 * 4);
  float* betak = (float*)alloc(512 * 4);
  float* c_qkv = (float*)alloc(1536 * 4);
  float* c1 = (float*)alloc(2048 * 4);
  float* c2 = (float*)alloc(512 * 4);
  float* dotqkv = (float*)alloc(1536 * 4);
  float* dot1   = (float*)alloc(2048 * 4);
  float* KVg   = (float*)alloc((size_t)512 * 3072 * 4);   // [quarter*128+bh][3072]
  float* Ksumg = (float*)alloc((size_t)512 * 48 * 4);
  unsigned short* AqkvT = (unsigned short*)alloc((size_t)1536 * 512 * 2);
  unsigned short* WoT   = (unsigned short*)alloc((size_t)512 * 512 * 2);
  unsigned short* A1T   = (unsigned short*)alloc((size_t)2048 * 512 * 2);
  unsigned short* A2T   = (unsigned short*)alloc((size_t)512 * 2048 * 2);
  unsigned short* WrT   = (unsigned short*)alloc((size_t)8 * 48 * 64 * 2);
  // big buffers (qkv and vT MUST be adjacent: g overlays both exactly)
  unsigned short* qkv   = (unsigned short*)alloc((size_t)NR * 1536 * 2);  // 96 MiB
  unsigned short* vT    = (unsigned short*)alloc((size_t)NR * 512 * 2);   // 32 MiB: vT then attn-out
  unsigned short* xb    = (unsigned short*)alloc((size_t)NR * 512 * 2);   // 32 MiB: bf16(x), lives to wo
  unsigned short* xrb   = (unsigned short*)alloc((size_t)NR * 512 * 2);   // 32 MiB
  unsigned short* attnO = vT;          // attn output reuses vT (dead after attn_A)
  unsigned short* g = qkv;             // fc1-out [NR][2048] bf16 = 128 MiB over qkv+vT (both dead)

  PrepArgs pa;
  for (int k = 0; k < 7; ++k) {
    pa.g[k] = (const float*)d_in[1 + k * 4 + 0];
    pa.b[k] = (const float*)d_in[1 + k * 4 + 1];
    pa.m[k] = (const float*)d_in[1 + k * 4 + 2];
    pa.v[k] = (const float*)d_in[1 + k * 4 + 3];
    pa.s[k] = sv_[k];
    pa.t[k] = tv_[k];
  }
  pa.wtq = wtq; pa.wtk = wtk; pa.betaq = betaq; pa.betak = betak;
  pa.dotqkv = dotqkv; pa.dot1 = dot1;

  prep_vectors<<<8, 256, 0, stream>>>(pa);
  // coalesced folds (64x64 tiles): grid (Nn/64, K/64)
  fold_wT2<<<dim3(8, 8), 256, 0, stream>>>(Wq, 512, 512, sv_[0], sv_[1], tv_[0], dotqkv, AqkvT);
  fold_wT2<<<dim3(8, 8), 256, 0, stream>>>(Wk, 512, 512, sv_[0], sv_[2], tv_[0], dotqkv + 512, AqkvT + 512 * 512);
  fold_wT2<<<dim3(8, 8), 256, 0, stream>>>(Wv, 512, 512, sv_[0], sv_[3], tv_[0], dotqkv + 1024, AqkvT + 1024 * 512);
  fold_wT2<<<dim3(8, 8), 256, 0, stream>>>(Wo, 512, 512, nullptr, nullptr, nullptr, nullptr, WoT);
  fold_wT2<<<dim3(32, 8), 256, 0, stream>>>(fc1W, 512, 2048, sv_[4], sv_[5], tv_[4], dot1, A1T);
  fold_wT2<<<dim3(8, 32), 256, 0, stream>>>(fc2W, 2048, 512, nullptr, sv_[6], nullptr, nullptr, A2T);
  for (int h = 0; h < 8; ++h)
    fold_wT<<<48, 64, 0, stream>>>(rffW + h * 64 * 48, 64, 48, WrT + h * 48 * 64);

  BiasArgs ba;
  ba.dotqkv = dotqkv; ba.dot1 = dot1; ba.bv = bv; ba.fc1b = fc1b; ba.fc2b = fc2b;
  ba.s1 = sv_[1]; ba.t1 = tv_[1]; ba.s2 = sv_[2]; ba.t2 = tv_[2]; ba.s3 = sv_[3]; ba.t3 = tv_[3];
  ba.s5 = sv_[5]; ba.t5 = tv_[5]; ba.s6 = sv_[6]; ba.t6 = tv_[6];
  ba.c_qkv = c_qkv; ba.c1 = c1; ba.c2 = c2;
  bias_fin<<<8, 256, 0, stream>>>(ba);

  cast_x<<<16384, 256, 0, stream>>>(x, xb, NR * 512);
  gemm_bf16<0><<<dim3(256, 12), 256, 0, stream>>>(xb, AqkvT, 512, 1536, c_qkv, nullptr, nullptr, qkv);
  mem_scan2<<<256, 1024, 0, stream>>>(qkv, betaq, betak);
  transpose_v<<<4096, 256, 0, stream>>>(qkv, vT);
  attn_A<<<dim3(128, 4), 512, 0, stream>>>(qkv, vT, WrT, rffb, KVg, Ksumg);
  attn_B<<<dim3(128, 4), 512, 0, stream>>>(qkv, WrT, rffb, KVg, Ksumg, attnO);
  gemm_bf16<1><<<dim3(256, 4), 256, 0, stream>>>(attnO, WoT, 512, 512, bo, xb, nullptr, xrb);
  gemm_bf16<2><<<dim3(256, 16), 256, 0, stream>>>(xrb, A1T, 512, 2048, c1, nullptr, nullptr, g);
  gemm_bf16<3><<<dim3(256, 4), 256, 0, stream>>>(g, A2T, 2048, 512, c2, xrb, (float*)d_out, nullptr);
}

// Round 11
// 463.541 us; speedup vs baseline: 1.2558x; 1.2558x over previous
//
#include <hip/hip_runtime.h>
#include <hip/hip_bf16.h>
#include <cstdint>
#include <math.h>

// SEDformer block: BN-folded bf16 MFMA GEMMs + in-place chunked EMA scan + RFF linear attention.
// L=2048 BS=16 D=512 H=8 DH=64 R=48 HID=2048; rows NR = L*BS = 32768.
// R11: attn reverted to R9 (best measured); all weight folds merged into ONE fold_all kernel
// (launch count 24 -> 12). GEMM unchanged (structural floor for these shapes).

typedef float  f32x4 __attribute__((ext_vector_type(4)));
typedef short  s16x8 __attribute__((ext_vector_type(8)));
typedef unsigned short u16x4 __attribute__((ext_vector_type(4)));

#define DEV static __device__ __forceinline__

constexpr int NR = 32768;          // L*BS

DEV float us2f(unsigned short u) {
  union { unsigned int i; float f; } z; z.i = ((unsigned int)u) << 16; return z.f;
}
DEV unsigned short f2bits(float f) {          // RNE f32 -> bf16 bits
  unsigned int u = __builtin_bit_cast(unsigned int, f);
  unsigned int r = u + 0x7fffu + ((u >> 16) & 1u);
  return (unsigned short)(r >> 16);
}

DEV void gload_lds16(const void* g, void* l) {
  __builtin_amdgcn_global_load_lds((__attribute__((address_space(1))) void*)g,
                                   (__attribute__((address_space(3))) void*)l, 16, 0, 0);
}

// ---------------- param prep: BN scale/shift + membrane betas + dot-acc zeroing ----------------
struct PrepArgs {
  const float *g[7], *b[7], *m[7], *v[7];   // bn1,bnq,bnk,bnv,bn2,bnf1,bnf2
  const float *wtq, *wtk;
  float *s[7], *t[7];
  float *betaq, *betak;
  float *dotqkv, *dot1;                     // 1536 / 2048, zeroed here
};

__global__ void prep_vectors(PrepArgs a) {
  int i = blockIdx.x * 256 + threadIdx.x;   // 0..2047
  const int dims[7] = {512, 512, 512, 512, 512, 2048, 512};
  #pragma unroll
  for (int k = 0; k < 7; ++k) {
    if (i < dims[k]) {
      float sc = a.g[k][i] * rsqrtf(a.v[k][i] + 1e-5f);
      a.s[k][i] = sc;
      a.t[k][i] = a.b[k][i] - a.m[k][i] * sc;
    }
  }
  if (i < 1536) a.dotqkv[i] = 0.f;
  if (i < 2048) a.dot1[i] = 0.f;
  if (i < 512) {
    float w = a.wtq[i];
    float sp = (w > 20.f) ? w : log1pf(expf(w));
    float be = 1.f - 1.f / (sp + 1.f);
    a.betaq[i] = fminf(fmaxf(be, 0.f), 0.9999f);
    w = a.wtk[i];
    sp = (w > 20.f) ? w : log1pf(expf(w));
    be = 1.f - 1.f / (sp + 1.f);
    a.betak[i] = fminf(fmaxf(be, 0.f), 0.9999f);
  }
}

// -------- unified fold kernel: all weights in one launch --------
// 64x64 LDS-transpose tile fold (device body); W[K][Nn] -> WT bf16 [Nn][K].
DEV void fold_tile(const float* __restrict__ W, int K, int Nn, int tx, int ty,
                   const float* scin, const float* scout,
                   const float* tin, float* dotacc,
                   unsigned short* __restrict__ WT,
                   float (*tile)[65], float (*dsum)[64]) {
  const int j0 = tx * 64, d0 = ty * 64;
  const int tid = threadIdx.x;
  const int j = tid & 63, r = tid >> 6;
  float dpart = 0.f;
  #pragma unroll
  for (int i = 0; i < 16; ++i) {
    int dd = i * 4 + r;
    float w = W[(size_t)(d0 + dd) * Nn + j0 + j];
    tile[dd][j] = w;
    if (tin) dpart += tin[d0 + dd] * w;
  }
  if (tin) dsum[r][j] = dpart;
  __syncthreads();
  if (tin && r == 0)
    atomicAdd(&dotacc[j0 + j], dsum[0][j] + dsum[1][j] + dsum[2][j] + dsum[3][j]);
  const int d = j;
  const float si = scin ? scin[d0 + d] : 1.f;
  #pragma unroll
  for (int i = 0; i < 16; ++i) {
    int jj = i * 4 + r;
    float so = scout ? scout[j0 + jj] : 1.f;
    WT[(size_t)(j0 + jj) * K + d0 + d] = f2bits(tile[d][jj] * si * so);
  }
}

struct FoldArgs {
  const float *Wq, *Wk, *Wv, *Wo, *fc1W, *fc2W, *rffW;
  const float *s0, *s1, *s2, *s3, *s4, *s5, *s6;
  const float *t0, *t4;
  float *dotqkv, *dot1;
  unsigned short *AqkvT, *WoT, *A1T, *A2T, *WrT;
};

// blocks: [0,64) Wq | [64,128) Wk | [128,192) Wv | [192,256) Wo |
//         [256,512) fc1 (32x8) | [512,768) fc2 (8x32) | [768,776) rffW heads
__global__ void fold_all(FoldArgs a) {
  __shared__ float tile[64][65];
  __shared__ float dsum[4][64];
  int bid = blockIdx.x;
  if (bid < 64) {
    fold_tile(a.Wq, 512, 512, bid & 7, bid >> 3, a.s0, a.s1, a.t0, a.dotqkv, a.AqkvT, tile, dsum);
  } else if (bid < 128) {
    int r = bid - 64;
    fold_tile(a.Wk, 512, 512, r & 7, r >> 3, a.s0, a.s2, a.t0, a.dotqkv + 512,
              a.AqkvT + 512 * 512, tile, dsum);
  } else if (bid < 192) {
    int r = bid - 128;
    fold_tile(a.Wv, 512, 512, r & 7, r >> 3, a.s0, a.s3, a.t0, a.dotqkv + 1024,
              a.AqkvT + 1024 * 512, tile, dsum);
  } else if (bid < 256) {
    int r = bid - 192;
    fold_tile(a.Wo, 512, 512, r & 7, r >> 3, nullptr, nullptr, nullptr, nullptr, a.WoT, tile, dsum);
  } else if (bid < 512) {
    int r = bid - 256;
    fold_tile(a.fc1W, 512, 2048, r & 31, r >> 5, a.s4, a.s5, a.t4, a.dot1, a.A1T, tile, dsum);
  } else if (bid < 768) {
    int r = bid - 512;
    fold_tile(a.fc2W, 2048, 512, r & 7, r >> 3, nullptr, a.s6, nullptr, nullptr, a.A2T, tile, dsum);
  } else {
    int h = bid - 768;                       // rffW[h][64][48] -> WrT[h*48 + j][64]
    const float* W = a.rffW + h * 64 * 48;
    unsigned short* WT = a.WrT + h * 48 * 64;
    for (int idx = threadIdx.x; idx < 48 * 64; idx += 256) {
      int j = idx >> 6, dd = idx & 63;
      WT[j * 64 + dd] = f2bits(W[dd * 48 + j]);
    }
  }
}

// -------- bias finalize --------
struct BiasArgs {
  const float *dotqkv, *dot1, *bv, *fc1b, *fc2b;
  const float *s1, *t1, *s2, *t2, *s3, *t3, *s5, *t5, *s6, *t6;
  float *c_qkv, *c1, *c2;
};
__global__ void bias_fin(BiasArgs a) {
  int i = blockIdx.x * 256 + threadIdx.x;   // 0..2047
  if (i < 512) {
    a.c_qkv[i]        = a.s1[i] * a.dotqkv[i]        + a.t1[i];
    a.c_qkv[512 + i]  = a.s2[i] * a.dotqkv[512 + i]  + a.t2[i];
    a.c_qkv[1024 + i] = a.s3[i] * (a.dotqkv[1024 + i] + a.bv[i]) + a.t3[i];
    a.c2[i]           = a.s6[i] * a.fc2b[i] + a.t6[i];
  }
  if (i < 2048) a.c1[i] = a.s5[i] * (a.dot1[i] + a.fc1b[i]) + a.t5[i];
}

// ---------------- cast x f32 -> bf16 ----------------
__global__ void cast_x(const float* __restrict__ x, unsigned short* __restrict__ xb, int n) {
  int i = (blockIdx.x * blockDim.x + threadIdx.x) * 4;
  if (i >= n) return;
  float4 v = *(const float4*)(x + i);
  u16x4 o = {f2bits(v.x), f2bits(v.y), f2bits(v.z), f2bits(v.w)};
  *(u16x4*)(xb + i) = o;
}

// ---------------- GEMM: C[M,N] = A[M,K](bf16) * BT[N,K](bf16)^T + bias, fused epilogues --------
// MODE 0: outb = bf16(acc+bias)
// MODE 1: outb = bf16(us2f(xresb) + acc + bias)
// MODE 2: outb = bf16(gelu(acc+bias))   (sigmoid-form tanh gelu)
// MODE 3: outf = us2f(xresb) + acc + bias
template <int MODE>
__global__ __launch_bounds__(256, 4) void gemm_bf16(
    const unsigned short* __restrict__ A, const unsigned short* __restrict__ BT,
    int K, int Nn, const float* __restrict__ bias,
    const unsigned short* __restrict__ xresb,
    float* __restrict__ outf, unsigned short* __restrict__ outb) {
  __shared__ __align__(16) unsigned short Ab[2][128 * 32];
  __shared__ __align__(16) unsigned short Bb[2][128 * 32];
  const int tid = threadIdx.x, w = tid >> 6, lane = tid & 63;
  const int l15 = lane & 15, lg = lane >> 4;
  const int row0 = blockIdx.x * 128, col0 = blockIdx.y * 128;
  const int wr = w >> 1, wc = w & 1;
  const unsigned short* Abase = A + (size_t)row0 * K;
  const unsigned short* Bbase = BT + (size_t)col0 * K;

  auto stage = [&](int buf, int kt) {
    #pragma unroll
    for (int s = 0; s < 2; ++s) {
      int c = s * 256 + w * 64 + lane;
      gload_lds16(Abase + (size_t)(c >> 2) * K + kt * 32 + (c & 3) * 8,
                  &Ab[buf][(s * 256 + w * 64) * 8]);
      gload_lds16(Bbase + (size_t)(c >> 2) * K + kt * 32 + (c & 3) * 8,
                  &Bb[buf][(s * 256 + w * 64) * 8]);
    }
  };

  const f32x4 fz = {0.f, 0.f, 0.f, 0.f};
  f32x4 acc[4][4];
  #pragma unroll
  for (int m = 0; m < 4; ++m)
    #pragma unroll
    for (int n = 0; n < 4; ++n) acc[m][n] = fz;

  stage(0, 0);
  __syncthreads();
  int cur = 0;
  const int nt = K >> 5;
  for (int kt = 0; kt < nt; ++kt) {
    if (kt + 1 < nt) stage(cur ^ 1, kt + 1);
    s16x8 af[4], bf[4];
    #pragma unroll
    for (int m = 0; m < 4; ++m)
      af[m] = *(const s16x8*)&Ab[cur][(wr * 64 + m * 16 + l15) * 32 + lg * 8];
    #pragma unroll
    for (int n = 0; n < 4; ++n)
      bf[n] = *(const s16x8*)&Bb[cur][(wc * 64 + n * 16 + l15) * 32 + lg * 8];
    #pragma unroll
    for (int m = 0; m < 4; ++m)
      #pragma unroll
      for (int n = 0; n < 4; ++n)
        acc[m][n] = __builtin_amdgcn_mfma_f32_16x16x32_bf16(af[m], bf[n], acc[m][n], 0, 0, 0);
    __syncthreads();
    cur ^= 1;
  }

  #pragma unroll
  for (int m = 0; m < 4; ++m) {
    #pragma unroll
    for (int q = 0; q < 4; ++q) {
      int row = row0 + wr * 64 + m * 16 + lg * 4 + q;
      #pragma unroll
      for (int n = 0; n < 4; ++n) {
        int col = col0 + wc * 64 + n * 16 + l15;
        float v = acc[m][n][q] + bias[col];
        size_t idx = (size_t)row * Nn + col;
        if constexpr (MODE == 0) {
          outb[idx] = f2bits(v);
        } else if constexpr (MODE == 1) {
          outb[idx] = f2bits(us2f(xresb[idx]) + v);
        } else if constexpr (MODE == 2) {
          float u2 = v * 1.5957691216f * (1.f + 0.044715f * v * v);
          float gl = v / (1.f + __expf(-u2));
          outb[idx] = f2bits(gl);
        } else {
          outf[idx] = us2f(xresb[idx]) + v;
        }
      }
    }
  }
}

// ---------------- membrane EMA scan over L, IN-PLACE, coalesced, 8-wide batched ----------------
__global__ __launch_bounds__(1024) void mem_scan2(unsigned short* __restrict__ qkv,
                         const float* __restrict__ betaq, const float* __restrict__ betak) {
  __shared__ float carry[16][64];
  __shared__ float pre[16][64];
  int cg = blockIdx.x & 15, b = blockIdx.x >> 4;
  int w = threadIdx.x >> 6, lane = threadIdx.x & 63;
  int ch = cg * 64 + lane;
  const float beta = (ch < 512) ? betaq[ch] : betak[ch - 512];
  const float om = 1.f - beta;
  unsigned short* base = qkv + (size_t)b * 1536 + ch;
  const size_t rs = 16 * 1536;     // shorts per L-step
  const int l0 = w * 128;

  float m = 0.f;
  for (int i = 0; i < 128; i += 8) {
    float v[8];
    #pragma unroll
    for (int j = 0; j < 8; ++j) v[j] = us2f(base[(size_t)(l0 + i + j) * rs]);
    #pragma unroll
    for (int j = 0; j < 8; ++j) m = beta * m + om * v[j];
  }
  carry[w][lane] = m;
  __syncthreads();
  if (w == 0) {
    float pw = beta;
    #pragma unroll
    for (int t = 0; t < 7; ++t) pw *= pw;   // beta^128
    float run = 0.f;
    for (int cc = 0; cc < 16; ++cc) {
      pre[cc][lane] = run;
      run = carry[cc][lane] + pw * run;
    }
  }
  __syncthreads();
  m = pre[w][lane];
  for (int i = 0; i < 128; i += 8) {
    float v[8];
    #pragma unroll
    for (int j = 0; j < 8; ++j) v[j] = us2f(base[(size_t)(l0 + i + j) * rs]);
    #pragma unroll
    for (int j = 0; j < 8; ++j) {
      m = beta * m + om * v[j];
      base[(size_t)(l0 + i + j) * rs] = f2bits(m);
    }
  }
}

// ---------------- transpose v: qkv v-cols -> vT[b,h,dh][L] ----------------
__global__ void transpose_v(const unsigned short* __restrict__ qkv, unsigned short* __restrict__ vT) {
  __shared__ __align__(16) unsigned short tile[64][72];
  int bid = blockIdx.x;
  int lt = bid & 31, h = (bid >> 5) & 7, b = bid >> 8;
  int l0 = lt * 64;
  int tid = threadIdx.x;
  int r = tid >> 2, cg = (tid & 3) * 16;
  const unsigned short* src = qkv + (size_t)((l0 + r) * 16 + b) * 1536 + 1024 + h * 64 + cg;
  *(s16x8*)&tile[r][cg] = *(const s16x8*)(src);
  *(s16x8*)&tile[r][cg + 8] = *(const s16x8*)(src + 8);
  __syncthreads();
  int dh = tid >> 2, lgp = (tid & 3) * 16;
  s16x8 o0, o1;
  #pragma unroll
  for (int j = 0; j < 8; ++j) {
    o0[j] = (short)tile[lgp + j][dh];
    o1[j] = (short)tile[lgp + 8 + j][dh];
  }
  unsigned short* dstp = vT + (size_t)((b * 8 + h) * 64 + dh) * 2048 + l0 + lgp;
  *(s16x8*)dstp = o0;
  *(s16x8*)(dstp + 8) = o1;
}

// ---------------- RFF linear attention phase A: KV + Ksum partials (no global atomics) ----------
__global__ __launch_bounds__(512, 1) void attn_A(
    const unsigned short* __restrict__ qkv, const unsigned short* __restrict__ vT,
    const unsigned short* __restrict__ WrT, const float* __restrict__ rffb,
    float* __restrict__ KVg, float* __restrict__ Ksumg) {
  __shared__ float KV[48][64];
  __shared__ float Ksum[48];
  __shared__ __align__(16) unsigned short phiT[8][48][72];

  const int tid = threadIdx.x;
  const int w = tid >> 6, lane = tid & 63, l15 = lane & 15, lg = lane >> 4;
  const int bh = blockIdx.x, b = bh >> 3, h = bh & 7;
  const int half = blockIdx.y;
  const f32x4 fz = {0.f, 0.f, 0.f, 0.f};
  constexpr float ISR = 0.14433756729740643f;   // 1/sqrt(48)

  for (int i = tid; i < 48 * 64; i += 512) (&KV[0][0])[i] = 0.f;
  if (tid < 48) Ksum[tid] = 0.f;
  __syncthreads();

  s16x8 wf[3][2];
  float bias_n[3];
  #pragma unroll
  for (int n = 0; n < 3; ++n) {
    int r = n * 16 + l15;
    bias_n[n] = rffb[h * 48 + r];
    #pragma unroll
    for (int ks = 0; ks < 2; ++ks)
      wf[n][ks] = *(const s16x8*)(WrT + (size_t)(h * 48 + r) * 64 + ks * 32 + lg * 8);
  }

  f32x4 kv[3][4];
  #pragma unroll
  for (int mm = 0; mm < 3; ++mm)
    #pragma unroll
    for (int nn = 0; nn < 4; ++nn) kv[mm][nn] = fz;
  float ks_acc[3] = {0.f, 0.f, 0.f};
  const size_t vbase = (size_t)(b * 8 + h) * 64 * 2048;

  for (int c = half * 16 + w; c < half * 16 + 16; c += 8) {
    const int l0 = c * 64;
    s16x8 kf[4][2];
    #pragma unroll
    for (int m = 0; m < 4; ++m) {
      size_t ro = (size_t)((l0 + m * 16 + l15) * 16 + b) * 1536 + 512 + h * 64;
      #pragma unroll
      for (int ks = 0; ks < 2; ++ks)
        kf[m][ks] = *(const s16x8*)(qkv + ro + ks * 32 + lg * 8);
    }
    f32x4 p[4][3];
    #pragma unroll
    for (int m = 0; m < 4; ++m)
      #pragma unroll
      for (int n = 0; n < 3; ++n) {
        p[m][n] = fz + bias_n[n];
        #pragma unroll
        for (int ks = 0; ks < 2; ++ks)
          p[m][n] = __builtin_amdgcn_mfma_f32_16x16x32_bf16(kf[m][ks], wf[n][ks], p[m][n], 0, 0, 0);
      }
    #pragma unroll
    for (int m = 0; m < 4; ++m)
      #pragma unroll
      for (int n = 0; n < 3; ++n) {
        u16x4 pk;
        #pragma unroll
        for (int q = 0; q < 4; ++q) {
          float pv = p[m][n][q];
          float ph = (pv > 0.f ? pv + 1.000001f : __expf(pv) + 1e-6f) * ISR;
          ks_acc[n] += ph;
          pk[q] = f2bits(ph);
        }
        *(u16x4*)&phiT[w][n * 16 + l15][m * 16 + lg * 4] = pk;
      }
    s16x8 pf[3][2], vf[4][2];
    #pragma unroll
    for (int mm = 0; mm < 3; ++mm)
      #pragma unroll
      for (int ks = 0; ks < 2; ++ks)
        pf[mm][ks] = *(const s16x8*)&phiT[w][mm * 16 + l15][ks * 32 + lg * 8];
    #pragma unroll
    for (int nn = 0; nn < 4; ++nn)
      #pragma unroll
      for (int ks = 0; ks < 2; ++ks)
        vf[nn][ks] = *(const s16x8*)(vT + vbase + (size_t)(nn * 16 + l15) * 2048 + l0 + ks * 32 + lg * 8);
    #pragma unroll
    for (int mm = 0; mm < 3; ++mm)
      #pragma unroll
      for (int nn = 0; nn < 4; ++nn)
        #pragma unroll
        for (int ks = 0; ks < 2; ++ks)
          kv[mm][nn] = __builtin_amdgcn_mfma_f32_16x16x32_bf16(pf[mm][ks], vf[nn][ks], kv[mm][nn], 0, 0, 0);
  }
  #pragma unroll
  for (int n = 0; n < 3; ++n) {
    float t = ks_acc[n];
    t += __shfl_xor(t, 16);
    t += __shfl_xor(t, 32);
    if (lane < 16) atomicAdd(&Ksum[n * 16 + lane], t);
  }
  #pragma unroll
  for (int mm = 0; mm < 3; ++mm)
    #pragma unroll
    for (int nn = 0; nn < 4; ++nn)
      #pragma unroll
      for (int q = 0; q < 4; ++q)
        atomicAdd(&KV[mm * 16 + lg * 4 + q][nn * 16 + l15], kv[mm][nn][q]);
  __syncthreads();

  float* dst = KVg + (size_t)(half * 128 + bh) * 3072;
  for (int i = tid; i < 48 * 64; i += 512) dst[i] = (&KV[0][0])[i];
  if (tid < 48) Ksumg[(half * 128 + bh) * 48 + tid] = Ksum[tid];
}

// ---------------- RFF linear attention phase B: phi_q, num/den, output ----------------
__global__ __launch_bounds__(512, 1) void attn_B(
    const unsigned short* __restrict__ qkv, const unsigned short* __restrict__ WrT,
    const float* __restrict__ rffb, const float* __restrict__ KVg,
    const float* __restrict__ Ksumg, unsigned short* __restrict__ attn) {
  __shared__ __align__(16) unsigned short KVT[80][72];
  __shared__ __align__(16) unsigned short phiQ[8][64][72];

  const int tid = threadIdx.x;
  const int w = tid >> 6, lane = tid & 63, l15 = lane & 15, lg = lane >> 4;
  const int bh = blockIdx.x, b = bh >> 3, h = bh & 7;
  const int half = blockIdx.y;
  const f32x4 fz = {0.f, 0.f, 0.f, 0.f};
  constexpr float ISR = 0.14433756729740643f;   // 1/sqrt(48)

  for (int i = tid; i < 8 * 64 * 72; i += 512) (&phiQ[0][0][0])[i] = 0;
  for (int i = tid; i < 80 * 72; i += 512) {
    int dhe = i / 72, rr = i - dhe * 72;
    float val = 0.f;
    if (rr < 48) {
      if (dhe < 64)
        val = KVg[(size_t)bh * 3072 + rr * 64 + dhe] + KVg[(size_t)(128 + bh) * 3072 + rr * 64 + dhe];
      else if (dhe == 64)
        val = fmaxf(Ksumg[bh * 48 + rr] + Ksumg[(128 + bh) * 48 + rr], 1e-6f);
    }
    (&KVT[0][0])[i] = f2bits(val);
  }
  __syncthreads();

  s16x8 wf[3][2];
  float bias_n[3];
  #pragma unroll
  for (int n = 0; n < 3; ++n) {
    int r = n * 16 + l15;
    bias_n[n] = rffb[h * 48 + r];
    #pragma unroll
    for (int ks = 0; ks < 2; ++ks)
      wf[n][ks] = *(const s16x8*)(WrT + (size_t)(h * 48 + r) * 64 + ks * 32 + lg * 8);
  }

  for (int c = half * 16 + w; c < half * 16 + 16; c += 8) {
    const int l0 = c * 64;
    s16x8 qf[4][2];
    #pragma unroll
    for (int m = 0; m < 4; ++m) {
      size_t ro = (size_t)((l0 + m * 16 + l15) * 16 + b) * 1536 + h * 64;
      #pragma unroll
      for (int ks = 0; ks < 2; ++ks)
        qf[m][ks] = *(const s16x8*)(qkv + ro + ks * 32 + lg * 8);
    }
    f32x4 p[4][3];
    #pragma unroll
    for (int m = 0; m < 4; ++m)
      #pragma unroll
      for (int n = 0; n < 3; ++n) {
        p[m][n] = fz + bias_n[n];
        #pragma unroll
        for (int ks = 0; ks < 2; ++ks)
          p[m][n] = __builtin_amdgcn_mfma_f32_16x16x32_bf16(qf[m][ks], wf[n][ks], p[m][n], 0, 0, 0);
      }
    #pragma unroll
    for (int m = 0; m < 4; ++m)
      #pragma unroll
      for (int n = 0; n < 3; ++n)
        #pragma unroll
        for (int q = 0; q < 4; ++q) {
          float pv = p[m][n][q];
          float ph = (pv > 0.f ? pv + 1.000001f : __expf(pv) + 1e-6f) * ISR;
          phiQ[w][m * 16 + lg * 4 + q][n * 16 + l15] = f2bits(ph);
        }
    s16x8 af[4][2], bv8[5][2];
    #pragma unroll
    for (int m = 0; m < 4; ++m)
      #pragma unroll
      for (int ks = 0; ks < 2; ++ks)
        af[m][ks] = *(const s16x8*)&phiQ[w][m * 16 + l15][ks * 32 + lg * 8];
    #pragma unroll
    for (int n5 = 0; n5 < 5; ++n5)
      #pragma unroll
      for (int ks = 0; ks < 2; ++ks)
        bv8[n5][ks] = *(const s16x8*)&KVT[n5 * 16 + l15][ks * 32 + lg * 8];
    f32x4 o[4][5];
    #pragma unroll
    for (int m = 0; m < 4; ++m)
      #pragma unroll
      for (int n5 = 0; n5 < 5; ++n5) {
        o[m][n5] = fz;
        #pragma unroll
        for (int ks = 0; ks < 2; ++ks)
          o[m][n5] = __builtin_amdgcn_mfma_f32_16x16x32_bf16(af[m][ks], bv8[n5][ks], o[m][n5], 0, 0, 0);
      }
    #pragma unroll
    for (int m = 0; m < 4; ++m)
      #pragma unroll
      for (int q = 0; q < 4; ++q) {
        float den = __shfl(o[m][4][q], lane & 48);
        float inv = 1.f / (den + 1e-6f);
        int gl = l0 + m * 16 + lg * 4 + q;
        size_t ob = (size_t)(gl * 16 + b) * 512 + h * 64;
        #pragma unroll
        for (int n = 0; n < 4; ++n)
          attn[ob + n * 16 + l15] = f2bits(o[m][n][q] * inv);
      }
  }
}

// ---------------- host ----------------
extern "C" void kernel_launch(void* const* d_in, const int* in_sizes, int n_in,
                              void* d_out, int out_size, void* d_ws, size_t ws_size,
                              hipStream_t stream) {
  (void)in_sizes; (void)n_in; (void)out_size; (void)ws_size;
  const float* x = (const float*)d_in[0];
  const float* Wq = (const float*)d_in[29];
  const float* Wk = (const float*)d_in[30];
  const float* Wv = (const float*)d_in[31];
  const float* bv = (const float*)d_in[32];
  const float* Wo = (const float*)d_in[33];
  const float* bo = (const float*)d_in[34];
  const float* wtq = (const float*)d_in[35];
  const float* wtk = (const float*)d_in[36];
  const float* rffW = (const float*)d_in[37];
  const float* rffb = (const float*)d_in[38];
  const float* fc1W = (const float*)d_in[39];
  const float* fc1b = (const float*)d_in[40];
  const float* fc2W = (const float*)d_in[41];
  const float* fc2b = (const float*)d_in[42];

  char* cur = (char*)d_ws;
  auto alloc = [&](size_t bytes) -> char* {
    char* r = cur;
    cur += (bytes + 255) & ~(size_t)255;
    return r;
  };
  float* sv_[7];
  float* tv_[7];
  const int dims[7] = {512, 512, 512, 512, 512, 2048, 512};
  for (int k = 0; k < 7; ++k) {
    sv_[k] = (float*)alloc(dims[k] * 4);
    tv_[k] = (float*)alloc(dims[k] * 4);
  }
  float* betaq = (float*)alloc(512 * 4);
  float* betak = (float*)alloc(512 * 4);
  float* c_qkv = (float*)alloc(1536 * 4);
  float* c1 = (float*)alloc(2048 * 4);
  float* c2 = (float*)alloc(512 * 4);
  float* dotqkv = (float*)alloc(1536 * 4);
  float* dot1   = (float*)alloc(2048 * 4);
  float* KVg   = (float*)alloc((size_t)256 * 3072 * 4);   // [half*128+bh][3072]
  float* Ksumg = (float*)alloc((size_t)256 * 48 * 4);
  unsigned short* AqkvT = (unsigned short*)alloc((size_t)1536 * 512 * 2);
  unsigned short* WoT   = (unsigned short*)alloc((size_t)512 * 512 * 2);
  unsigned short* A1T   = (unsigned short*)alloc((size_t)2048 * 512 * 2);
  unsigned short* A2T   = (unsigned short*)alloc((size_t)512 * 2048 * 2);
  unsigned short* WrT   = (unsigned short*)alloc((size_t)8 * 48 * 64 * 2);
  // big buffers (qkv and vT MUST be adjacent: g overlays both exactly)
  unsigned short* qkv   = (unsigned short*)alloc((size_t)NR * 1536 * 2);  // 96 MiB
  unsigned short* vT    = (unsigned short*)alloc((size_t)NR * 512 * 2);   // 32 MiB: vT then attn-out
  unsigned short* xb    = (unsigned short*)alloc((size_t)NR * 512 * 2);   // 32 MiB: bf16(x), lives to wo
  unsigned short* xrb   = (unsigned short*)alloc((size_t)NR * 512 * 2);   // 32 MiB
  unsigned short* attnO = vT;          // attn output reuses vT (dead after attn_A)
  unsigned short* g = qkv;             // fc1-out [NR][2048] bf16 = 128 MiB over qkv+vT (both dead)

  PrepArgs pa;
  for (int k = 0; k < 7; ++k) {
    pa.g[k] = (const float*)d_in[1 + k * 4 + 0];
    pa.b[k] = (const float*)d_in[1 + k * 4 + 1];
    pa.m[k] = (const float*)d_in[1 + k * 4 + 2];
    pa.v[k] = (const float*)d_in[1 + k * 4 + 3];
    pa.s[k] = sv_[k];
    pa.t[k] = tv_[k];
  }
  pa.wtq = wtq; pa.wtk = wtk; pa.betaq = betaq; pa.betak = betak;
  pa.dotqkv = dotqkv; pa.dot1 = dot1;

  prep_vectors<<<8, 256, 0, stream>>>(pa);

  FoldArgs fa;
  fa.Wq = Wq; fa.Wk = Wk; fa.Wv = Wv; fa.Wo = Wo; fa.fc1W = fc1W; fa.fc2W = fc2W; fa.rffW = rffW;
  fa.s0 = sv_[0]; fa.s1 = sv_[1]; fa.s2 = sv_[2]; fa.s3 = sv_[3];
  fa.s4 = sv_[4]; fa.s5 = sv_[5]; fa.s6 = sv_[6];
  fa.t0 = tv_[0]; fa.t4 = tv_[4];
  fa.dotqkv = dotqkv; fa.dot1 = dot1;
  fa.AqkvT = AqkvT; fa.WoT = WoT; fa.A1T = A1T; fa.A2T = A2T; fa.WrT = WrT;
  fold_all<<<776, 256, 0, stream>>>(fa);

  BiasArgs ba;
  ba.dotqkv = dotqkv; ba.dot1 = dot1; ba.bv = bv; ba.fc1b = fc1b; ba.fc2b = fc2b;
  ba.s1 = sv_[1]; ba.t1 = tv_[1]; ba.s2 = sv_[2]; ba.t2 = tv_[2]; ba.s3 = sv_[3]; ba.t3 = tv_[3];
  ba.s5 = sv_[5]; ba.t5 = tv_[5]; ba.s6 = sv_[6]; ba.t6 = tv_[6];
  ba.c_qkv = c_qkv; ba.c1 = c1; ba.c2 = c2;
  bias_fin<<<8, 256, 0, stream>>>(ba);

  cast_x<<<16384, 256, 0, stream>>>(x, xb, NR * 512);
  gemm_bf16<0><<<dim3(256, 12), 256, 0, stream>>>(xb, AqkvT, 512, 1536, c_qkv, nullptr, nullptr, qkv);
  mem_scan2<<<256, 1024, 0, stream>>>(qkv, betaq, betak);
  transpose_v<<<4096, 256, 0, stream>>>(qkv, vT);
  attn_A<<<dim3(128, 2), 512, 0, stream>>>(qkv, vT, WrT, rffb, KVg, Ksumg);
  attn_B<<<dim3(128, 2), 512, 0, stream>>>(qkv, WrT, rffb, KVg, Ksumg, attnO);
  gemm_bf16<1><<<dim3(256, 4), 256, 0, stream>>>(attnO, WoT, 512, 512, bo, xb, nullptr, xrb);
  gemm_bf16<2><<<dim3(256, 16), 256, 0, stream>>>(xrb, A1T, 512, 2048, c1, nullptr, nullptr, g);
  gemm_bf16<3><<<dim3(256, 4), 256, 0, stream>>>(g, A2T, 2048, 512, c2, xrb, (float*)d_out, nullptr);
}

// Round 12
// 448.253 us; speedup vs baseline: 1.2986x; 1.0341x over previous
//
#include <hip/hip_runtime.h>
#include <hip/hip_bf16.h>
#include <cstdint>
#include <math.h>

// SEDformer block: BN-folded bf16 MFMA GEMMs + in-place chunked EMA scan + RFF linear attention.
// L=2048 BS=16 D=512 H=8 DH=64 R=48 HID=2048; rows NR = L*BS = 32768.
// R12: more kernel merging (proven R11 lever): cast_x absorbed into fold_all;
// transpose_v absorbed into mem_scan kernel (disjoint qkv columns -> race-free).
// Launches 12 -> 10. GEMM + attn identical to R11 (best measured).

typedef float  f32x4 __attribute__((ext_vector_type(4)));
typedef short  s16x8 __attribute__((ext_vector_type(8)));
typedef unsigned short u16x4 __attribute__((ext_vector_type(4)));

#define DEV static __device__ __forceinline__

constexpr int NR = 32768;          // L*BS

DEV float us2f(unsigned short u) {
  union { unsigned int i; float f; } z; z.i = ((unsigned int)u) << 16; return z.f;
}
DEV unsigned short f2bits(float f) {          // RNE f32 -> bf16 bits
  unsigned int u = __builtin_bit_cast(unsigned int, f);
  unsigned int r = u + 0x7fffu + ((u >> 16) & 1u);
  return (unsigned short)(r >> 16);
}

DEV void gload_lds16(const void* g, void* l) {
  __builtin_amdgcn_global_load_lds((__attribute__((address_space(1))) void*)g,
                                   (__attribute__((address_space(3))) void*)l, 16, 0, 0);
}

// ---------------- param prep: BN scale/shift + membrane betas + dot-acc zeroing ----------------
struct PrepArgs {
  const float *g[7], *b[7], *m[7], *v[7];   // bn1,bnq,bnk,bnv,bn2,bnf1,bnf2
  const float *wtq, *wtk;
  float *s[7], *t[7];
  float *betaq, *betak;
  float *dotqkv, *dot1;                     // 1536 / 2048, zeroed here
};

__global__ void prep_vectors(PrepArgs a) {
  int i = blockIdx.x * 256 + threadIdx.x;   // 0..2047
  const int dims[7] = {512, 512, 512, 512, 512, 2048, 512};
  #pragma unroll
  for (int k = 0; k < 7; ++k) {
    if (i < dims[k]) {
      float sc = a.g[k][i] * rsqrtf(a.v[k][i] + 1e-5f);
      a.s[k][i] = sc;
      a.t[k][i] = a.b[k][i] - a.m[k][i] * sc;
    }
  }
  if (i < 1536) a.dotqkv[i] = 0.f;
  if (i < 2048) a.dot1[i] = 0.f;
  if (i < 512) {
    float w = a.wtq[i];
    float sp = (w > 20.f) ? w : log1pf(expf(w));
    float be = 1.f - 1.f / (sp + 1.f);
    a.betaq[i] = fminf(fmaxf(be, 0.f), 0.9999f);
    w = a.wtk[i];
    sp = (w > 20.f) ? w : log1pf(expf(w));
    be = 1.f - 1.f / (sp + 1.f);
    a.betak[i] = fminf(fmaxf(be, 0.f), 0.9999f);
  }
}

// -------- unified fold + cast kernel: all weights + x-cast in one launch --------
// 64x64 LDS-transpose tile fold (device body); W[K][Nn] -> WT bf16 [Nn][K].
DEV void fold_tile(const float* __restrict__ W, int K, int Nn, int tx, int ty,
                   const float* scin, const float* scout,
                   const float* tin, float* dotacc,
                   unsigned short* __restrict__ WT,
                   float (*tile)[65], float (*dsum)[64]) {
  const int j0 = tx * 64, d0 = ty * 64;
  const int tid = threadIdx.x;
  const int j = tid & 63, r = tid >> 6;
  float dpart = 0.f;
  #pragma unroll
  for (int i = 0; i < 16; ++i) {
    int dd = i * 4 + r;
    float w = W[(size_t)(d0 + dd) * Nn + j0 + j];
    tile[dd][j] = w;
    if (tin) dpart += tin[d0 + dd] * w;
  }
  if (tin) dsum[r][j] = dpart;
  __syncthreads();
  if (tin && r == 0)
    atomicAdd(&dotacc[j0 + j], dsum[0][j] + dsum[1][j] + dsum[2][j] + dsum[3][j]);
  const int d = j;
  const float si = scin ? scin[d0 + d] : 1.f;
  #pragma unroll
  for (int i = 0; i < 16; ++i) {
    int jj = i * 4 + r;
    float so = scout ? scout[j0 + jj] : 1.f;
    WT[(size_t)(j0 + jj) * K + d0 + d] = f2bits(tile[d][jj] * si * so);
  }
}

struct FoldArgs {
  const float *Wq, *Wk, *Wv, *Wo, *fc1W, *fc2W, *rffW, *x;
  const float *s0, *s1, *s2, *s3, *s4, *s5, *s6;
  const float *t0, *t4;
  float *dotqkv, *dot1;
  unsigned short *AqkvT, *WoT, *A1T, *A2T, *WrT, *xb;
};

// blocks: [0,64) Wq | [64,128) Wk | [128,192) Wv | [192,256) Wo |
//         [256,512) fc1 (32x8) | [512,768) fc2 (8x32) | [768,776) rffW heads |
//         [776, 776+16384) cast x -> xb (4 floats/thread)
__global__ void fold_all(FoldArgs a) {
  __shared__ float tile[64][65];
  __shared__ float dsum[4][64];
  int bid = blockIdx.x;
  if (bid < 64) {
    fold_tile(a.Wq, 512, 512, bid & 7, bid >> 3, a.s0, a.s1, a.t0, a.dotqkv, a.AqkvT, tile, dsum);
  } else if (bid < 128) {
    int r = bid - 64;
    fold_tile(a.Wk, 512, 512, r & 7, r >> 3, a.s0, a.s2, a.t0, a.dotqkv + 512,
              a.AqkvT + 512 * 512, tile, dsum);
  } else if (bid < 192) {
    int r = bid - 128;
    fold_tile(a.Wv, 512, 512, r & 7, r >> 3, a.s0, a.s3, a.t0, a.dotqkv + 1024,
              a.AqkvT + 1024 * 512, tile, dsum);
  } else if (bid < 256) {
    int r = bid - 192;
    fold_tile(a.Wo, 512, 512, r & 7, r >> 3, nullptr, nullptr, nullptr, nullptr, a.WoT, tile, dsum);
  } else if (bid < 512) {
    int r = bid - 256;
    fold_tile(a.fc1W, 512, 2048, r & 31, r >> 5, a.s4, a.s5, a.t4, a.dot1, a.A1T, tile, dsum);
  } else if (bid < 768) {
    int r = bid - 512;
    fold_tile(a.fc2W, 2048, 512, r & 7, r >> 3, nullptr, a.s6, nullptr, nullptr, a.A2T, tile, dsum);
  } else if (bid < 776) {
    int h = bid - 768;                       // rffW[h][64][48] -> WrT[h*48 + j][64]
    const float* W = a.rffW + h * 64 * 48;
    unsigned short* WT = a.WrT + h * 48 * 64;
    for (int idx = threadIdx.x; idx < 48 * 64; idx += 256) {
      int j = idx >> 6, dd = idx & 63;
      WT[j * 64 + dd] = f2bits(W[dd * 48 + j]);
    }
  } else {
    int i = ((bid - 776) * 256 + threadIdx.x) * 4;
    if (i < NR * 512) {
      float4 v = *(const float4*)(a.x + i);
      u16x4 o = {f2bits(v.x), f2bits(v.y), f2bits(v.z), f2bits(v.w)};
      *(u16x4*)(a.xb + i) = o;
    }
  }
}

// -------- bias finalize --------
struct BiasArgs {
  const float *dotqkv, *dot1, *bv, *fc1b, *fc2b;
  const float *s1, *t1, *s2, *t2, *s3, *t3, *s5, *t5, *s6, *t6;
  float *c_qkv, *c1, *c2;
};
__global__ void bias_fin(BiasArgs a) {
  int i = blockIdx.x * 256 + threadIdx.x;   // 0..2047
  if (i < 512) {
    a.c_qkv[i]        = a.s1[i] * a.dotqkv[i]        + a.t1[i];
    a.c_qkv[512 + i]  = a.s2[i] * a.dotqkv[512 + i]  + a.t2[i];
    a.c_qkv[1024 + i] = a.s3[i] * (a.dotqkv[1024 + i] + a.bv[i]) + a.t3[i];
    a.c2[i]           = a.s6[i] * a.fc2b[i] + a.t6[i];
  }
  if (i < 2048) a.c1[i] = a.s5[i] * (a.dot1[i] + a.fc1b[i]) + a.t5[i];
}

// ---------------- GEMM: C[M,N] = A[M,K](bf16) * BT[N,K](bf16)^T + bias, fused epilogues --------
// MODE 0: outb = bf16(acc+bias)
// MODE 1: outb = bf16(us2f(xresb) + acc + bias)
// MODE 2: outb = bf16(gelu(acc+bias))   (sigmoid-form tanh gelu)
// MODE 3: outf = us2f(xresb) + acc + bias
template <int MODE>
__global__ __launch_bounds__(256, 4) void gemm_bf16(
    const unsigned short* __restrict__ A, const unsigned short* __restrict__ BT,
    int K, int Nn, const float* __restrict__ bias,
    const unsigned short* __restrict__ xresb,
    float* __restrict__ outf, unsigned short* __restrict__ outb) {
  __shared__ __align__(16) unsigned short Ab[2][128 * 32];
  __shared__ __align__(16) unsigned short Bb[2][128 * 32];
  const int tid = threadIdx.x, w = tid >> 6, lane = tid & 63;
  const int l15 = lane & 15, lg = lane >> 4;
  const int row0 = blockIdx.x * 128, col0 = blockIdx.y * 128;
  const int wr = w >> 1, wc = w & 1;
  const unsigned short* Abase = A + (size_t)row0 * K;
  const unsigned short* Bbase = BT + (size_t)col0 * K;

  auto stage = [&](int buf, int kt) {
    #pragma unroll
    for (int s = 0; s < 2; ++s) {
      int c = s * 256 + w * 64 + lane;
      gload_lds16(Abase + (size_t)(c >> 2) * K + kt * 32 + (c & 3) * 8,
                  &Ab[buf][(s * 256 + w * 64) * 8]);
      gload_lds16(Bbase + (size_t)(c >> 2) * K + kt * 32 + (c & 3) * 8,
                  &Bb[buf][(s * 256 + w * 64) * 8]);
    }
  };

  const f32x4 fz = {0.f, 0.f, 0.f, 0.f};
  f32x4 acc[4][4];
  #pragma unroll
  for (int m = 0; m < 4; ++m)
    #pragma unroll
    for (int n = 0; n < 4; ++n) acc[m][n] = fz;

  stage(0, 0);
  __syncthreads();
  int cur = 0;
  const int nt = K >> 5;
  for (int kt = 0; kt < nt; ++kt) {
    if (kt + 1 < nt) stage(cur ^ 1, kt + 1);
    s16x8 af[4], bf[4];
    #pragma unroll
    for (int m = 0; m < 4; ++m)
      af[m] = *(const s16x8*)&Ab[cur][(wr * 64 + m * 16 + l15) * 32 + lg * 8];
    #pragma unroll
    for (int n = 0; n < 4; ++n)
      bf[n] = *(const s16x8*)&Bb[cur][(wc * 64 + n * 16 + l15) * 32 + lg * 8];
    #pragma unroll
    for (int m = 0; m < 4; ++m)
      #pragma unroll
      for (int n = 0; n < 4; ++n)
        acc[m][n] = __builtin_amdgcn_mfma_f32_16x16x32_bf16(af[m], bf[n], acc[m][n], 0, 0, 0);
    __syncthreads();
    cur ^= 1;
  }

  #pragma unroll
  for (int m = 0; m < 4; ++m) {
    #pragma unroll
    for (int q = 0; q < 4; ++q) {
      int row = row0 + wr * 64 + m * 16 + lg * 4 + q;
      #pragma unroll
      for (int n = 0; n < 4; ++n) {
        int col = col0 + wc * 64 + n * 16 + l15;
        float v = acc[m][n][q] + bias[col];
        size_t idx = (size_t)row * Nn + col;
        if constexpr (MODE == 0) {
          outb[idx] = f2bits(v);
        } else if constexpr (MODE == 1) {
          outb[idx] = f2bits(us2f(xresb[idx]) + v);
        } else if constexpr (MODE == 2) {
          float u2 = v * 1.5957691216f * (1.f + 0.044715f * v * v);
          float gl = v / (1.f + __expf(-u2));
          outb[idx] = f2bits(gl);
        } else {
          outf[idx] = us2f(xresb[idx]) + v;
        }
      }
    }
  }
}

// ---------------- merged membrane scan + v-transpose (disjoint qkv columns) ----------------
// blocks [0,256): in-place EMA scan on q/k cols (1024 thr: 16 waves x 64 ch).
// blocks [256,1280): v-transpose, 4 tiles per block (tid>>8 selects tile, private LDS regions).
__global__ __launch_bounds__(1024) void scan_tr(unsigned short* __restrict__ qkv,
                         const float* __restrict__ betaq, const float* __restrict__ betak,
                         unsigned short* __restrict__ vT) {
  if (blockIdx.x < 256) {
    __shared__ float carry[16][64];
    __shared__ float pre[16][64];
    int cg = blockIdx.x & 15, b = blockIdx.x >> 4;
    int w = threadIdx.x >> 6, lane = threadIdx.x & 63;
    int ch = cg * 64 + lane;
    const float beta = (ch < 512) ? betaq[ch] : betak[ch - 512];
    const float om = 1.f - beta;
    unsigned short* base = qkv + (size_t)b * 1536 + ch;
    const size_t rs = 16 * 1536;     // shorts per L-step
    const int l0 = w * 128;

    float m = 0.f;
    for (int i = 0; i < 128; i += 8) {
      float v[8];
      #pragma unroll
      for (int j = 0; j < 8; ++j) v[j] = us2f(base[(size_t)(l0 + i + j) * rs]);
      #pragma unroll
      for (int j = 0; j < 8; ++j) m = beta * m + om * v[j];
    }
    carry[w][lane] = m;
    __syncthreads();
    if (w == 0) {
      float pw = beta;
      #pragma unroll
      for (int t = 0; t < 7; ++t) pw *= pw;   // beta^128
      float run = 0.f;
      for (int cc = 0; cc < 16; ++cc) {
        pre[cc][lane] = run;
        run = carry[cc][lane] + pw * run;
      }
    }
    __syncthreads();
    m = pre[w][lane];
    for (int i = 0; i < 128; i += 8) {
      float v[8];
      #pragma unroll
      for (int j = 0; j < 8; ++j) v[j] = us2f(base[(size_t)(l0 + i + j) * rs]);
      #pragma unroll
      for (int j = 0; j < 8; ++j) {
        m = beta * m + om * v[j];
        base[(size_t)(l0 + i + j) * rs] = f2bits(m);
      }
    }
  } else {
    __shared__ __align__(16) unsigned short tile4[4][64][72];
    int sub = threadIdx.x >> 8;              // 0..3: which tile
    int t = (blockIdx.x - 256) * 4 + sub;    // 0..4095
    int lt = t & 31, h = (t >> 5) & 7, b = t >> 8;
    int l0 = lt * 64;
    int tid = threadIdx.x & 255;
    int r = tid >> 2, cg = (tid & 3) * 16;
    const unsigned short* src = qkv + (size_t)((l0 + r) * 16 + b) * 1536 + 1024 + h * 64 + cg;
    *(s16x8*)&tile4[sub][r][cg] = *(const s16x8*)(src);
    *(s16x8*)&tile4[sub][r][cg + 8] = *(const s16x8*)(src + 8);
    __syncthreads();
    int dh = tid >> 2, lgp = (tid & 3) * 16;
    s16x8 o0, o1;
    #pragma unroll
    for (int j = 0; j < 8; ++j) {
      o0[j] = (short)tile4[sub][lgp + j][dh];
      o1[j] = (short)tile4[sub][lgp + 8 + j][dh];
    }
    unsigned short* dstp = vT + (size_t)((b * 8 + h) * 64 + dh) * 2048 + l0 + lgp;
    *(s16x8*)dstp = o0;
    *(s16x8*)(dstp + 8) = o1;
  }
}

// ---------------- RFF linear attention phase A: KV + Ksum partials (no global atomics) ----------
__global__ __launch_bounds__(512, 1) void attn_A(
    const unsigned short* __restrict__ qkv, const unsigned short* __restrict__ vT,
    const unsigned short* __restrict__ WrT, const float* __restrict__ rffb,
    float* __restrict__ KVg, float* __restrict__ Ksumg) {
  __shared__ float KV[48][64];
  __shared__ float Ksum[48];
  __shared__ __align__(16) unsigned short phiT[8][48][72];

  const int tid = threadIdx.x;
  const int w = tid >> 6, lane = tid & 63, l15 = lane & 15, lg = lane >> 4;
  const int bh = blockIdx.x, b = bh >> 3, h = bh & 7;
  const int half = blockIdx.y;
  const f32x4 fz = {0.f, 0.f, 0.f, 0.f};
  constexpr float ISR = 0.14433756729740643f;   // 1/sqrt(48)

  for (int i = tid; i < 48 * 64; i += 512) (&KV[0][0])[i] = 0.f;
  if (tid < 48) Ksum[tid] = 0.f;
  __syncthreads();

  s16x8 wf[3][2];
  float bias_n[3];
  #pragma unroll
  for (int n = 0; n < 3; ++n) {
    int r = n * 16 + l15;
    bias_n[n] = rffb[h * 48 + r];
    #pragma unroll
    for (int ks = 0; ks < 2; ++ks)
      wf[n][ks] = *(const s16x8*)(WrT + (size_t)(h * 48 + r) * 64 + ks * 32 + lg * 8);
  }

  f32x4 kv[3][4];
  #pragma unroll
  for (int mm = 0; mm < 3; ++mm)
    #pragma unroll
    for (int nn = 0; nn < 4; ++nn) kv[mm][nn] = fz;
  float ks_acc[3] = {0.f, 0.f, 0.f};
  const size_t vbase = (size_t)(b * 8 + h) * 64 * 2048;

  for (int c = half * 16 + w; c < half * 16 + 16; c += 8) {
    const int l0 = c * 64;
    s16x8 kf[4][2];
    #pragma unroll
    for (int m = 0; m < 4; ++m) {
      size_t ro = (size_t)((l0 + m * 16 + l15) * 16 + b) * 1536 + 512 + h * 64;
      #pragma unroll
      for (int ks = 0; ks < 2; ++ks)
        kf[m][ks] = *(const s16x8*)(qkv + ro + ks * 32 + lg * 8);
    }
    f32x4 p[4][3];
    #pragma unroll
    for (int m = 0; m < 4; ++m)
      #pragma unroll
      for (int n = 0; n < 3; ++n) {
        p[m][n] = fz + bias_n[n];
        #pragma unroll
        for (int ks = 0; ks < 2; ++ks)
          p[m][n] = __builtin_amdgcn_mfma_f32_16x16x32_bf16(kf[m][ks], wf[n][ks], p[m][n], 0, 0, 0);
      }
    #pragma unroll
    for (int m = 0; m < 4; ++m)
      #pragma unroll
      for (int n = 0; n < 3; ++n) {
        u16x4 pk;
        #pragma unroll
        for (int q = 0; q < 4; ++q) {
          float pv = p[m][n][q];
          float ph = (pv > 0.f ? pv + 1.000001f : __expf(pv) + 1e-6f) * ISR;
          ks_acc[n] += ph;
          pk[q] = f2bits(ph);
        }
        *(u16x4*)&phiT[w][n * 16 + l15][m * 16 + lg * 4] = pk;
      }
    s16x8 pf[3][2], vf[4][2];
    #pragma unroll
    for (int mm = 0; mm < 3; ++mm)
      #pragma unroll
      for (int ks = 0; ks < 2; ++ks)
        pf[mm][ks] = *(const s16x8*)&phiT[w][mm * 16 + l15][ks * 32 + lg * 8];
    #pragma unroll
    for (int nn = 0; nn < 4; ++nn)
      #pragma unroll
      for (int ks = 0; ks < 2; ++ks)
        vf[nn][ks] = *(const s16x8*)(vT + vbase + (size_t)(nn * 16 + l15) * 2048 + l0 + ks * 32 + lg * 8);
    #pragma unroll
    for (int mm = 0; mm < 3; ++mm)
      #pragma unroll
      for (int nn = 0; nn < 4; ++nn)
        #pragma unroll
        for (int ks = 0; ks < 2; ++ks)
          kv[mm][nn] = __builtin_amdgcn_mfma_f32_16x16x32_bf16(pf[mm][ks], vf[nn][ks], kv[mm][nn], 0, 0, 0);
  }
  #pragma unroll
  for (int n = 0; n < 3; ++n) {
    float t = ks_acc[n];
    t += __shfl_xor(t, 16);
    t += __shfl_xor(t, 32);
    if (lane < 16) atomicAdd(&Ksum[n * 16 + lane], t);
  }
  #pragma unroll
  for (int mm = 0; mm < 3; ++mm)
    #pragma unroll
    for (int nn = 0; nn < 4; ++nn)
      #pragma unroll
      for (int q = 0; q < 4; ++q)
        atomicAdd(&KV[mm * 16 + lg * 4 + q][nn * 16 + l15], kv[mm][nn][q]);
  __syncthreads();

  float* dst = KVg + (size_t)(half * 128 + bh) * 3072;
  for (int i = tid; i < 48 * 64; i += 512) dst[i] = (&KV[0][0])[i];
  if (tid < 48) Ksumg[(half * 128 + bh) * 48 + tid] = Ksum[tid];
}

// ---------------- RFF linear attention phase B: phi_q, num/den, output ----------------
__global__ __launch_bounds__(512, 1) void attn_B(
    const unsigned short* __restrict__ qkv, const unsigned short* __restrict__ WrT,
    const float* __restrict__ rffb, const float* __restrict__ KVg,
    const float* __restrict__ Ksumg, unsigned short* __restrict__ attn) {
  __shared__ __align__(16) unsigned short KVT[80][72];
  __shared__ __align__(16) unsigned short phiQ[8][64][72];

  const int tid = threadIdx.x;
  const int w = tid >> 6, lane = tid & 63, l15 = lane & 15, lg = lane >> 4;
  const int bh = blockIdx.x, b = bh >> 3, h = bh & 7;
  const int half = blockIdx.y;
  const f32x4 fz = {0.f, 0.f, 0.f, 0.f};
  constexpr float ISR = 0.14433756729740643f;   // 1/sqrt(48)

  for (int i = tid; i < 8 * 64 * 72; i += 512) (&phiQ[0][0][0])[i] = 0;
  for (int i = tid; i < 80 * 72; i += 512) {
    int dhe = i / 72, rr = i - dhe * 72;
    float val = 0.f;
    if (rr < 48) {
      if (dhe < 64)
        val = KVg[(size_t)bh * 3072 + rr * 64 + dhe] + KVg[(size_t)(128 + bh) * 3072 + rr * 64 + dhe];
      else if (dhe == 64)
        val = fmaxf(Ksumg[bh * 48 + rr] + Ksumg[(128 + bh) * 48 + rr], 1e-6f);
    }
    (&KVT[0][0])[i] = f2bits(val);
  }
  __syncthreads();

  s16x8 wf[3][2];
  float bias_n[3];
  #pragma unroll
  for (int n = 0; n < 3; ++n) {
    int r = n * 16 + l15;
    bias_n[n] = rffb[h * 48 + r];
    #pragma unroll
    for (int ks = 0; ks < 2; ++ks)
      wf[n][ks] = *(const s16x8*)(WrT + (size_t)(h * 48 + r) * 64 + ks * 32 + lg * 8);
  }

  for (int c = half * 16 + w; c < half * 16 + 16; c += 8) {
    const int l0 = c * 64;
    s16x8 qf[4][2];
    #pragma unroll
    for (int m = 0; m < 4; ++m) {
      size_t ro = (size_t)((l0 + m * 16 + l15) * 16 + b) * 1536 + h * 64;
      #pragma unroll
      for (int ks = 0; ks < 2; ++ks)
        qf[m][ks] = *(const s16x8*)(qkv + ro + ks * 32 + lg * 8);
    }
    f32x4 p[4][3];
    #pragma unroll
    for (int m = 0; m < 4; ++m)
      #pragma unroll
      for (int n = 0; n < 3; ++n) {
        p[m][n] = fz + bias_n[n];
        #pragma unroll
        for (int ks = 0; ks < 2; ++ks)
          p[m][n] = __builtin_amdgcn_mfma_f32_16x16x32_bf16(qf[m][ks], wf[n][ks], p[m][n], 0, 0, 0);
      }
    #pragma unroll
    for (int m = 0; m < 4; ++m)
      #pragma unroll
      for (int n = 0; n < 3; ++n)
        #pragma unroll
        for (int q = 0; q < 4; ++q) {
          float pv = p[m][n][q];
          float ph = (pv > 0.f ? pv + 1.000001f : __expf(pv) + 1e-6f) * ISR;
          phiQ[w][m * 16 + lg * 4 + q][n * 16 + l15] = f2bits(ph);
        }
    s16x8 af[4][2], bv8[5][2];
    #pragma unroll
    for (int m = 0; m < 4; ++m)
      #pragma unroll
      for (int ks = 0; ks < 2; ++ks)
        af[m][ks] = *(const s16x8*)&phiQ[w][m * 16 + l15][ks * 32 + lg * 8];
    #pragma unroll
    for (int n5 = 0; n5 < 5; ++n5)
      #pragma unroll
      for (int ks = 0; ks < 2; ++ks)
        bv8[n5][ks] = *(const s16x8*)&KVT[n5 * 16 + l15][ks * 32 + lg * 8];
    f32x4 o[4][5];
    #pragma unroll
    for (int m = 0; m < 4; ++m)
      #pragma unroll
      for (int n5 = 0; n5 < 5; ++n5) {
        o[m][n5] = fz;
        #pragma unroll
        for (int ks = 0; ks < 2; ++ks)
          o[m][n5] = __builtin_amdgcn_mfma_f32_16x16x32_bf16(af[m][ks], bv8[n5][ks], o[m][n5], 0, 0, 0);
      }
    #pragma unroll
    for (int m = 0; m < 4; ++m)
      #pragma unroll
      for (int q = 0; q < 4; ++q) {
        float den = __shfl(o[m][4][q], lane & 48);
        float inv = 1.f / (den + 1e-6f);
        int gl = l0 + m * 16 + lg * 4 + q;
        size_t ob = (size_t)(gl * 16 + b) * 512 + h * 64;
        #pragma unroll
        for (int n = 0; n < 4; ++n)
          attn[ob + n * 16 + l15] = f2bits(o[m][n][q] * inv);
      }
  }
}

// ---------------- host ----------------
extern "C" void kernel_launch(void* const* d_in, const int* in_sizes, int n_in,
                              void* d_out, int out_size, void* d_ws, size_t ws_size,
                              hipStream_t stream) {
  (void)in_sizes; (void)n_in; (void)out_size; (void)ws_size;
  const float* x = (const float*)d_in[0];
  const float* Wq = (const float*)d_in[29];
  const float* Wk = (const float*)d_in[30];
  const float* Wv = (const float*)d_in[31];
  const float* bv = (const float*)d_in[32];
  const float* Wo = (const float*)d_in[33];
  const float* bo = (const float*)d_in[34];
  const float* wtq = (const float*)d_in[35];
  const float* wtk = (const float*)d_in[36];
  const float* rffW = (const float*)d_in[37];
  const float* rffb = (const float*)d_in[38];
  const float* fc1W = (const float*)d_in[39];
  const float* fc1b = (const float*)d_in[40];
  const float* fc2W = (const float*)d_in[41];
  const float* fc2b = (const float*)d_in[42];

  char* cur = (char*)d_ws;
  auto alloc = [&](size_t bytes) -> char* {
    char* r = cur;
    cur += (bytes + 255) & ~(size_t)255;
    return r;
  };
  float* sv_[7];
  float* tv_[7];
  const int dims[7] = {512, 512, 512, 512, 512, 2048, 512};
  for (int k = 0; k < 7; ++k) {
    sv_[k] = (float*)alloc(dims[k] * 4);
    tv_[k] = (float*)alloc(dims[k] * 4);
  }
  float* betaq = (float*)alloc(512 * 4);
  float* betak = (float*)alloc(512 * 4);
  float* c_qkv = (float*)alloc(1536 * 4);
  float* c1 = (float*)alloc(2048 * 4);
  float* c2 = (float*)alloc(512 * 4);
  float* dotqkv = (float*)alloc(1536 * 4);
  float* dot1   = (float*)alloc(2048 * 4);
  float* KVg   = (float*)alloc((size_t)256 * 3072 * 4);   // [half*128+bh][3072]
  float* Ksumg = (float*)alloc((size_t)256 * 48 * 4);
  unsigned short* AqkvT = (unsigned short*)alloc((size_t)1536 * 512 * 2);
  unsigned short* WoT   = (unsigned short*)alloc((size_t)512 * 512 * 2);
  unsigned short* A1T   = (unsigned short*)alloc((size_t)2048 * 512 * 2);
  unsigned short* A2T   = (unsigned short*)alloc((size_t)512 * 2048 * 2);
  unsigned short* WrT   = (unsigned short*)alloc((size_t)8 * 48 * 64 * 2);
  // big buffers (qkv and vT MUST be adjacent: g overlays both exactly)
  unsigned short* qkv   = (unsigned short*)alloc((size_t)NR * 1536 * 2);  // 96 MiB
  unsigned short* vT    = (unsigned short*)alloc((size_t)NR * 512 * 2);   // 32 MiB: vT then attn-out
  unsigned short* xb    = (unsigned short*)alloc((size_t)NR * 512 * 2);   // 32 MiB: bf16(x), lives to wo
  unsigned short* xrb   = (unsigned short*)alloc((size_t)NR * 512 * 2);   // 32 MiB
  unsigned short* attnO = vT;          // attn output reuses vT (dead after attn_A)
  unsigned short* g = qkv;             // fc1-out [NR][2048] bf16 = 128 MiB over qkv+vT (both dead)

  PrepArgs pa;
  for (int k = 0; k < 7; ++k) {
    pa.g[k] = (const float*)d_in[1 + k * 4 + 0];
    pa.b[k] = (const float*)d_in[1 + k * 4 + 1];
    pa.m[k] = (const float*)d_in[1 + k * 4 + 2];
    pa.v[k] = (const float*)d_in[1 + k * 4 + 3];
    pa.s[k] = sv_[k];
    pa.t[k] = tv_[k];
  }
  pa.wtq = wtq; pa.wtk = wtk; pa.betaq = betaq; pa.betak = betak;
  pa.dotqkv = dotqkv; pa.dot1 = dot1;

  prep_vectors<<<8, 256, 0, stream>>>(pa);

  FoldArgs fa;
  fa.Wq = Wq; fa.Wk = Wk; fa.Wv = Wv; fa.Wo = Wo; fa.fc1W = fc1W; fa.fc2W = fc2W; fa.rffW = rffW;
  fa.x = x;
  fa.s0 = sv_[0]; fa.s1 = sv_[1]; fa.s2 = sv_[2]; fa.s3 = sv_[3];
  fa.s4 = sv_[4]; fa.s5 = sv_[5]; fa.s6 = sv_[6];
  fa.t0 = tv_[0]; fa.t4 = tv_[4];
  fa.dotqkv = dotqkv; fa.dot1 = dot1;
  fa.AqkvT = AqkvT; fa.WoT = WoT; fa.A1T = A1T; fa.A2T = A2T; fa.WrT = WrT;
  fa.xb = xb;
  fold_all<<<776 + 16384, 256, 0, stream>>>(fa);

  BiasArgs ba;
  ba.dotqkv = dotqkv; ba.dot1 = dot1; ba.bv = bv; ba.fc1b = fc1b; ba.fc2b = fc2b;
  ba.s1 = sv_[1]; ba.t1 = tv_[1]; ba.s2 = sv_[2]; ba.t2 = tv_[2]; ba.s3 = sv_[3]; ba.t3 = tv_[3];
  ba.s5 = sv_[5]; ba.t5 = tv_[5]; ba.s6 = sv_[6]; ba.t6 = tv_[6];
  ba.c_qkv = c_qkv; ba.c1 = c1; ba.c2 = c2;
  bias_fin<<<8, 256, 0, stream>>>(ba);

  gemm_bf16<0><<<dim3(256, 12), 256, 0, stream>>>(xb, AqkvT, 512, 1536, c_qkv, nullptr, nullptr, qkv);
  scan_tr<<<1280, 1024, 0, stream>>>(qkv, betaq, betak, vT);
  attn_A<<<dim3(128, 2), 512, 0, stream>>>(qkv, vT, WrT, rffb, KVg, Ksumg);
  attn_B<<<dim3(128, 2), 512, 0, stream>>>(qkv, WrT, rffb, KVg, Ksumg, attnO);
  gemm_bf16<1><<<dim3(256, 4), 256, 0, stream>>>(attnO, WoT, 512, 512, bo, xb, nullptr, xrb);
  gemm_bf16<2><<<dim3(256, 16), 256, 0, stream>>>(xrb, A1T, 512, 2048, c1, nullptr, nullptr, g);
  gemm_bf16<3><<<dim3(256, 4), 256, 0, stream>>>(g, A2T, 2048, 512, c2, xrb, (float*)d_out, nullptr);
}

// Round 13
// 442.276 us; speedup vs baseline: 1.3161x; 1.0135x over previous
//
#include <hip/hip_runtime.h>
#include <hip/hip_bf16.h>
#include <cstdint>
#include <math.h>

// SEDformer block: BN-folded bf16 MFMA GEMMs + in-place chunked EMA scan + RFF linear attention.
// L=2048 BS=16 D=512 H=8 DH=64 R=48 HID=2048; rows NR = L*BS = 32768.
// R13: prep_vectors eliminated — BN scales computed inline (fold_tile LDS slices, bias_fin
// per-element, scan_tr per-channel betas); dot zeroing via hipMemsetAsync nodes.
// Launches 10 -> 9 (+2 memset nodes). GEMM/attn identical to R12 (best measured, 448us).

typedef float  f32x4 __attribute__((ext_vector_type(4)));
typedef short  s16x8 __attribute__((ext_vector_type(8)));
typedef unsigned short u16x4 __attribute__((ext_vector_type(4)));

#define DEV static __device__ __forceinline__

constexpr int NR = 32768;          // L*BS

DEV float us2f(unsigned short u) {
  union { unsigned int i; float f; } z; z.i = ((unsigned int)u) << 16; return z.f;
}
DEV unsigned short f2bits(float f) {          // RNE f32 -> bf16 bits
  unsigned int u = __builtin_bit_cast(unsigned int, f);
  unsigned int r = u + 0x7fffu + ((u >> 16) & 1u);
  return (unsigned short)(r >> 16);
}

DEV void gload_lds16(const void* g, void* l) {
  __builtin_amdgcn_global_load_lds((__attribute__((address_space(1))) void*)g,
                                   (__attribute__((address_space(3))) void*)l, 16, 0, 0);
}

// -------- unified fold + cast kernel: all weights + x-cast in one launch --------
// 64x64 LDS-transpose tile fold; W[K][Nn] -> WT bf16 [Nn][K]; BN scales computed inline.
DEV void fold_tile(const float* __restrict__ W, int K, int Nn, int tx, int ty,
                   const float* gin, const float* bin, const float* min_, const float* vin,
                   const float* gout, const float* vout,
                   float* dotacc, unsigned short* __restrict__ WT,
                   float (*tile)[65], float (*dsum)[64],
                   float* s_in, float* t_in, float* s_out) {
  const int j0 = tx * 64, d0 = ty * 64;
  const int tid = threadIdx.x;
  const int j = tid & 63, r = tid >> 6;
  if (gin && tid < 64) {
    float sc = gin[d0 + tid] * rsqrtf(vin[d0 + tid] + 1e-5f);
    s_in[tid] = sc;
    t_in[tid] = bin[d0 + tid] - min_[d0 + tid] * sc;
  }
  if (gout && tid >= 64 && tid < 128) {
    int jj = tid - 64;
    s_out[jj] = gout[j0 + jj] * rsqrtf(vout[j0 + jj] + 1e-5f);
  }
  __syncthreads();
  float dpart = 0.f;
  #pragma unroll
  for (int i = 0; i < 16; ++i) {
    int dd = i * 4 + r;
    float w = W[(size_t)(d0 + dd) * Nn + j0 + j];
    tile[dd][j] = w;
    if (gin) dpart += t_in[dd] * w;
  }
  if (gin) dsum[r][j] = dpart;
  __syncthreads();
  if (gin && r == 0)
    atomicAdd(&dotacc[j0 + j], dsum[0][j] + dsum[1][j] + dsum[2][j] + dsum[3][j]);
  const int d = j;
  const float si = gin ? s_in[d] : 1.f;
  #pragma unroll
  for (int i = 0; i < 16; ++i) {
    int jj = i * 4 + r;
    float so = gout ? s_out[jj] : 1.f;
    WT[(size_t)(j0 + jj) * K + d0 + d] = f2bits(tile[d][jj] * si * so);
  }
}

struct FoldArgs {
  const float *Wq, *Wk, *Wv, *Wo, *fc1W, *fc2W, *rffW, *x;
  const float *g[7], *b[7], *m[7], *v[7];   // bn1,bnq,bnk,bnv,bn2,bnf1,bnf2
  float *dotqkv, *dot1;
  unsigned short *AqkvT, *WoT, *A1T, *A2T, *WrT, *xb;
};

// blocks: [0,64) Wq | [64,128) Wk | [128,192) Wv | [192,256) Wo |
//         [256,512) fc1 (32x8) | [512,768) fc2 (8x32) | [768,776) rffW heads |
//         [776, 776+16384) cast x -> xb (4 floats/thread)
__global__ void fold_all(FoldArgs a) {
  __shared__ float tile[64][65];
  __shared__ float dsum[4][64];
  __shared__ float s_in[64], t_in[64], s_out[64];
  int bid = blockIdx.x;
  if (bid < 64) {
    fold_tile(a.Wq, 512, 512, bid & 7, bid >> 3, a.g[0], a.b[0], a.m[0], a.v[0],
              a.g[1], a.v[1], a.dotqkv, a.AqkvT, tile, dsum, s_in, t_in, s_out);
  } else if (bid < 128) {
    int r = bid - 64;
    fold_tile(a.Wk, 512, 512, r & 7, r >> 3, a.g[0], a.b[0], a.m[0], a.v[0],
              a.g[2], a.v[2], a.dotqkv + 512, a.AqkvT + 512 * 512, tile, dsum, s_in, t_in, s_out);
  } else if (bid < 192) {
    int r = bid - 128;
    fold_tile(a.Wv, 512, 512, r & 7, r >> 3, a.g[0], a.b[0], a.m[0], a.v[0],
              a.g[3], a.v[3], a.dotqkv + 1024, a.AqkvT + 1024 * 512, tile, dsum, s_in, t_in, s_out);
  } else if (bid < 256) {
    int r = bid - 192;
    fold_tile(a.Wo, 512, 512, r & 7, r >> 3, nullptr, nullptr, nullptr, nullptr,
              nullptr, nullptr, nullptr, a.WoT, tile, dsum, s_in, t_in, s_out);
  } else if (bid < 512) {
    int r = bid - 256;
    fold_tile(a.fc1W, 512, 2048, r & 31, r >> 5, a.g[4], a.b[4], a.m[4], a.v[4],
              a.g[5], a.v[5], a.dot1, a.A1T, tile, dsum, s_in, t_in, s_out);
  } else if (bid < 768) {
    int r = bid - 512;
    fold_tile(a.fc2W, 2048, 512, r & 7, r >> 3, nullptr, nullptr, nullptr, nullptr,
              a.g[6], a.v[6], nullptr, a.A2T, tile, dsum, s_in, t_in, s_out);
  } else if (bid < 776) {
    int h = bid - 768;                       // rffW[h][64][48] -> WrT[h*48 + j][64]
    const float* W = a.rffW + h * 64 * 48;
    unsigned short* WT = a.WrT + h * 48 * 64;
    for (int idx = threadIdx.x; idx < 48 * 64; idx += 256) {
      int j = idx >> 6, dd = idx & 63;
      WT[j * 64 + dd] = f2bits(W[dd * 48 + j]);
    }
  } else {
    int i = ((bid - 776) * 256 + threadIdx.x) * 4;
    if (i < NR * 512) {
      float4 v = *(const float4*)(a.x + i);
      u16x4 o = {f2bits(v.x), f2bits(v.y), f2bits(v.z), f2bits(v.w)};
      *(u16x4*)(a.xb + i) = o;
    }
  }
}

// -------- bias finalize (BN scales inline) --------
struct BiasArgs {
  const float *dotqkv, *dot1, *bv, *fc1b, *fc2b;
  const float *g[7], *b[7], *m[7], *v[7];
  float *c_qkv, *c1, *c2;
};
__global__ void bias_fin(BiasArgs a) {
  int i = blockIdx.x * 256 + threadIdx.x;   // 0..2047
  if (i < 512) {
    float s1 = a.g[1][i] * rsqrtf(a.v[1][i] + 1e-5f);
    float t1 = a.b[1][i] - a.m[1][i] * s1;
    a.c_qkv[i] = s1 * a.dotqkv[i] + t1;
    float s2 = a.g[2][i] * rsqrtf(a.v[2][i] + 1e-5f);
    float t2 = a.b[2][i] - a.m[2][i] * s2;
    a.c_qkv[512 + i] = s2 * a.dotqkv[512 + i] + t2;
    float s3 = a.g[3][i] * rsqrtf(a.v[3][i] + 1e-5f);
    float t3 = a.b[3][i] - a.m[3][i] * s3;
    a.c_qkv[1024 + i] = s3 * (a.dotqkv[1024 + i] + a.bv[i]) + t3;
    float s6 = a.g[6][i] * rsqrtf(a.v[6][i] + 1e-5f);
    float t6 = a.b[6][i] - a.m[6][i] * s6;
    a.c2[i] = s6 * a.fc2b[i] + t6;
  }
  if (i < 2048) {
    float s5 = a.g[5][i] * rsqrtf(a.v[5][i] + 1e-5f);
    float t5 = a.b[5][i] - a.m[5][i] * s5;
    a.c1[i] = s5 * (a.dot1[i] + a.fc1b[i]) + t5;
  }
}

// ---------------- GEMM: C[M,N] = A[M,K](bf16) * BT[N,K](bf16)^T + bias, fused epilogues --------
// MODE 0: outb = bf16(acc+bias)
// MODE 1: outb = bf16(us2f(xresb) + acc + bias)
// MODE 2: outb = bf16(gelu(acc+bias))   (sigmoid-form tanh gelu)
// MODE 3: outf = us2f(xresb) + acc + bias
template <int MODE>
__global__ __launch_bounds__(256, 4) void gemm_bf16(
    const unsigned short* __restrict__ A, const unsigned short* __restrict__ BT,
    int K, int Nn, const float* __restrict__ bias,
    const unsigned short* __restrict__ xresb,
    float* __restrict__ outf, unsigned short* __restrict__ outb) {
  __shared__ __align__(16) unsigned short Ab[2][128 * 32];
  __shared__ __align__(16) unsigned short Bb[2][128 * 32];
  const int tid = threadIdx.x, w = tid >> 6, lane = tid & 63;
  const int l15 = lane & 15, lg = lane >> 4;
  const int row0 = blockIdx.x * 128, col0 = blockIdx.y * 128;
  const int wr = w >> 1, wc = w & 1;
  const unsigned short* Abase = A + (size_t)row0 * K;
  const unsigned short* Bbase = BT + (size_t)col0 * K;

  auto stage = [&](int buf, int kt) {
    #pragma unroll
    for (int s = 0; s < 2; ++s) {
      int c = s * 256 + w * 64 + lane;
      gload_lds16(Abase + (size_t)(c >> 2) * K + kt * 32 + (c & 3) * 8,
                  &Ab[buf][(s * 256 + w * 64) * 8]);
      gload_lds16(Bbase + (size_t)(c >> 2) * K + kt * 32 + (c & 3) * 8,
                  &Bb[buf][(s * 256 + w * 64) * 8]);
    }
  };

  const f32x4 fz = {0.f, 0.f, 0.f, 0.f};
  f32x4 acc[4][4];
  #pragma unroll
  for (int m = 0; m < 4; ++m)
    #pragma unroll
    for (int n = 0; n < 4; ++n) acc[m][n] = fz;

  stage(0, 0);
  __syncthreads();
  int cur = 0;
  const int nt = K >> 5;
  for (int kt = 0; kt < nt; ++kt) {
    if (kt + 1 < nt) stage(cur ^ 1, kt + 1);
    s16x8 af[4], bf[4];
    #pragma unroll
    for (int m = 0; m < 4; ++m)
      af[m] = *(const s16x8*)&Ab[cur][(wr * 64 + m * 16 + l15) * 32 + lg * 8];
    #pragma unroll
    for (int n = 0; n < 4; ++n)
      bf[n] = *(const s16x8*)&Bb[cur][(wc * 64 + n * 16 + l15) * 32 + lg * 8];
    #pragma unroll
    for (int m = 0; m < 4; ++m)
      #pragma unroll
      for (int n = 0; n < 4; ++n)
        acc[m][n] = __builtin_amdgcn_mfma_f32_16x16x32_bf16(af[m], bf[n], acc[m][n], 0, 0, 0);
    __syncthreads();
    cur ^= 1;
  }

  #pragma unroll
  for (int m = 0; m < 4; ++m) {
    #pragma unroll
    for (int q = 0; q < 4; ++q) {
      int row = row0 + wr * 64 + m * 16 + lg * 4 + q;
      #pragma unroll
      for (int n = 0; n < 4; ++n) {
        int col = col0 + wc * 64 + n * 16 + l15;
        float v = acc[m][n][q] + bias[col];
        size_t idx = (size_t)row * Nn + col;
        if constexpr (MODE == 0) {
          outb[idx] = f2bits(v);
        } else if constexpr (MODE == 1) {
          outb[idx] = f2bits(us2f(xresb[idx]) + v);
        } else if constexpr (MODE == 2) {
          float u2 = v * 1.5957691216f * (1.f + 0.044715f * v * v);
          float gl = v / (1.f + __expf(-u2));
          outb[idx] = f2bits(gl);
        } else {
          outf[idx] = us2f(xresb[idx]) + v;
        }
      }
    }
  }
}

// ---------------- merged membrane scan + v-transpose (disjoint qkv columns) ----------------
// blocks [0,256): in-place EMA scan on q/k cols; beta computed inline from wtau.
// blocks [256,1280): v-transpose, 4 tiles per block.
__global__ __launch_bounds__(1024) void scan_tr(unsigned short* __restrict__ qkv,
                         const float* __restrict__ wtq, const float* __restrict__ wtk,
                         unsigned short* __restrict__ vT) {
  if (blockIdx.x < 256) {
    __shared__ float carry[16][64];
    __shared__ float pre[16][64];
    int cg = blockIdx.x & 15, b = blockIdx.x >> 4;
    int w = threadIdx.x >> 6, lane = threadIdx.x & 63;
    int ch = cg * 64 + lane;
    float w0 = (ch < 512) ? wtq[ch] : wtk[ch - 512];
    float sp = (w0 > 20.f) ? w0 : log1pf(expf(w0));
    const float beta = fminf(fmaxf(1.f - 1.f / (sp + 1.f), 0.f), 0.9999f);
    const float om = 1.f - beta;
    unsigned short* base = qkv + (size_t)b * 1536 + ch;
    const size_t rs = 16 * 1536;     // shorts per L-step
    const int l0 = w * 128;

    float m = 0.f;
    for (int i = 0; i < 128; i += 8) {
      float v[8];
      #pragma unroll
      for (int j = 0; j < 8; ++j) v[j] = us2f(base[(size_t)(l0 + i + j) * rs]);
      #pragma unroll
      for (int j = 0; j < 8; ++j) m = beta * m + om * v[j];
    }
    carry[w][lane] = m;
    __syncthreads();
    if (w == 0) {
      float pw = beta;
      #pragma unroll
      for (int t = 0; t < 7; ++t) pw *= pw;   // beta^128
      float run = 0.f;
      for (int cc = 0; cc < 16; ++cc) {
        pre[cc][lane] = run;
        run = carry[cc][lane] + pw * run;
      }
    }
    __syncthreads();
    m = pre[w][lane];
    for (int i = 0; i < 128; i += 8) {
      float v[8];
      #pragma unroll
      for (int j = 0; j < 8; ++j) v[j] = us2f(base[(size_t)(l0 + i + j) * rs]);
      #pragma unroll
      for (int j = 0; j < 8; ++j) {
        m = beta * m + om * v[j];
        base[(size_t)(l0 + i + j) * rs] = f2bits(m);
      }
    }
  } else {
    __shared__ __align__(16) unsigned short tile4[4][64][72];
    int sub = threadIdx.x >> 8;              // 0..3: which tile
    int t = (blockIdx.x - 256) * 4 + sub;    // 0..4095
    int lt = t & 31, h = (t >> 5) & 7, b = t >> 8;
    int l0 = lt * 64;
    int tid = threadIdx.x & 255;
    int r = tid >> 2, cg = (tid & 3) * 16;
    const unsigned short* src = qkv + (size_t)((l0 + r) * 16 + b) * 1536 + 1024 + h * 64 + cg;
    *(s16x8*)&tile4[sub][r][cg] = *(const s16x8*)(src);
    *(s16x8*)&tile4[sub][r][cg + 8] = *(const s16x8*)(src + 8);
    __syncthreads();
    int dh = tid >> 2, lgp = (tid & 3) * 16;
    s16x8 o0, o1;
    #pragma unroll
    for (int j = 0; j < 8; ++j) {
      o0[j] = (short)tile4[sub][lgp + j][dh];
      o1[j] = (short)tile4[sub][lgp + 8 + j][dh];
    }
    unsigned short* dstp = vT + (size_t)((b * 8 + h) * 64 + dh) * 2048 + l0 + lgp;
    *(s16x8*)dstp = o0;
    *(s16x8*)(dstp + 8) = o1;
  }
}

// ---------------- RFF linear attention phase A: KV + Ksum partials (no global atomics) ----------
__global__ __launch_bounds__(512, 1) void attn_A(
    const unsigned short* __restrict__ qkv, const unsigned short* __restrict__ vT,
    const unsigned short* __restrict__ WrT, const float* __restrict__ rffb,
    float* __restrict__ KVg, float* __restrict__ Ksumg) {
  __shared__ float KV[48][64];
  __shared__ float Ksum[48];
  __shared__ __align__(16) unsigned short phiT[8][48][72];

  const int tid = threadIdx.x;
  const int w = tid >> 6, lane = tid & 63, l15 = lane & 15, lg = lane >> 4;
  const int bh = blockIdx.x, b = bh >> 3, h = bh & 7;
  const int half = blockIdx.y;
  const f32x4 fz = {0.f, 0.f, 0.f, 0.f};
  constexpr float ISR = 0.14433756729740643f;   // 1/sqrt(48)

  for (int i = tid; i < 48 * 64; i += 512) (&KV[0][0])[i] = 0.f;
  if (tid < 48) Ksum[tid] = 0.f;
  __syncthreads();

  s16x8 wf[3][2];
  float bias_n[3];
  #pragma unroll
  for (int n = 0; n < 3; ++n) {
    int r = n * 16 + l15;
    bias_n[n] = rffb[h * 48 + r];
    #pragma unroll
    for (int ks = 0; ks < 2; ++ks)
      wf[n][ks] = *(const s16x8*)(WrT + (size_t)(h * 48 + r) * 64 + ks * 32 + lg * 8);
  }

  f32x4 kv[3][4];
  #pragma unroll
  for (int mm = 0; mm < 3; ++mm)
    #pragma unroll
    for (int nn = 0; nn < 4; ++nn) kv[mm][nn] = fz;
  float ks_acc[3] = {0.f, 0.f, 0.f};
  const size_t vbase = (size_t)(b * 8 + h) * 64 * 2048;

  for (int c = half * 16 + w; c < half * 16 + 16; c += 8) {
    const int l0 = c * 64;
    s16x8 kf[4][2];
    #pragma unroll
    for (int m = 0; m < 4; ++m) {
      size_t ro = (size_t)((l0 + m * 16 + l15) * 16 + b) * 1536 + 512 + h * 64;
      #pragma unroll
      for (int ks = 0; ks < 2; ++ks)
        kf[m][ks] = *(const s16x8*)(qkv + ro + ks * 32 + lg * 8);
    }
    f32x4 p[4][3];
    #pragma unroll
    for (int m = 0; m < 4; ++m)
      #pragma unroll
      for (int n = 0; n < 3; ++n) {
        p[m][n] = fz + bias_n[n];
        #pragma unroll
        for (int ks = 0; ks < 2; ++ks)
          p[m][n] = __builtin_amdgcn_mfma_f32_16x16x32_bf16(kf[m][ks], wf[n][ks], p[m][n], 0, 0, 0);
      }
    #pragma unroll
    for (int m = 0; m < 4; ++m)
      #pragma unroll
      for (int n = 0; n < 3; ++n) {
        u16x4 pk;
        #pragma unroll
        for (int q = 0; q < 4; ++q) {
          float pv = p[m][n][q];
          float ph = (pv > 0.f ? pv + 1.000001f : __expf(pv) + 1e-6f) * ISR;
          ks_acc[n] += ph;
          pk[q] = f2bits(ph);
        }
        *(u16x4*)&phiT[w][n * 16 + l15][m * 16 + lg * 4] = pk;
      }
    s16x8 pf[3][2], vf[4][2];
    #pragma unroll
    for (int mm = 0; mm < 3; ++mm)
      #pragma unroll
      for (int ks = 0; ks < 2; ++ks)
        pf[mm][ks] = *(const s16x8*)&phiT[w][mm * 16 + l15][ks * 32 + lg * 8];
    #pragma unroll
    for (int nn = 0; nn < 4; ++nn)
      #pragma unroll
      for (int ks = 0; ks < 2; ++ks)
        vf[nn][ks] = *(const s16x8*)(vT + vbase + (size_t)(nn * 16 + l15) * 2048 + l0 + ks * 32 + lg * 8);
    #pragma unroll
    for (int mm = 0; mm < 3; ++mm)
      #pragma unroll
      for (int nn = 0; nn < 4; ++nn)
        #pragma unroll
        for (int ks = 0; ks < 2; ++ks)
          kv[mm][nn] = __builtin_amdgcn_mfma_f32_16x16x32_bf16(pf[mm][ks], vf[nn][ks], kv[mm][nn], 0, 0, 0);
  }
  #pragma unroll
  for (int n = 0; n < 3; ++n) {
    float t = ks_acc[n];
    t += __shfl_xor(t, 16);
    t += __shfl_xor(t, 32);
    if (lane < 16) atomicAdd(&Ksum[n * 16 + lane], t);
  }
  #pragma unroll
  for (int mm = 0; mm < 3; ++mm)
    #pragma unroll
    for (int nn = 0; nn < 4; ++nn)
      #pragma unroll
      for (int q = 0; q < 4; ++q)
        atomicAdd(&KV[mm * 16 + lg * 4 + q][nn * 16 + l15], kv[mm][nn][q]);
  __syncthreads();

  float* dst = KVg + (size_t)(half * 128 + bh) * 3072;
  for (int i = tid; i < 48 * 64; i += 512) dst[i] = (&KV[0][0])[i];
  if (tid < 48) Ksumg[(half * 128 + bh) * 48 + tid] = Ksum[tid];
}

// ---------------- RFF linear attention phase B: phi_q, num/den, output ----------------
__global__ __launch_bounds__(512, 1) void attn_B(
    const unsigned short* __restrict__ qkv, const unsigned short* __restrict__ WrT,
    const float* __restrict__ rffb, const float* __restrict__ KVg,
    const float* __restrict__ Ksumg, unsigned short* __restrict__ attn) {
  __shared__ __align__(16) unsigned short KVT[80][72];
  __shared__ __align__(16) unsigned short phiQ[8][64][72];

  const int tid = threadIdx.x;
  const int w = tid >> 6, lane = tid & 63, l15 = lane & 15, lg = lane >> 4;
  const int bh = blockIdx.x, b = bh >> 3, h = bh & 7;
  const int half = blockIdx.y;
  const f32x4 fz = {0.f, 0.f, 0.f, 0.f};
  constexpr float ISR = 0.14433756729740643f;   // 1/sqrt(48)

  for (int i = tid; i < 8 * 64 * 72; i += 512) (&phiQ[0][0][0])[i] = 0;
  for (int i = tid; i < 80 * 72; i += 512) {
    int dhe = i / 72, rr = i - dhe * 72;
    float val = 0.f;
    if (rr < 48) {
      if (dhe < 64)
        val = KVg[(size_t)bh * 3072 + rr * 64 + dhe] + KVg[(size_t)(128 + bh) * 3072 + rr * 64 + dhe];
      else if (dhe == 64)
        val = fmaxf(Ksumg[bh * 48 + rr] + Ksumg[(128 + bh) * 48 + rr], 1e-6f);
    }
    (&KVT[0][0])[i] = f2bits(val);
  }
  __syncthreads();

  s16x8 wf[3][2];
  float bias_n[3];
  #pragma unroll
  for (int n = 0; n < 3; ++n) {
    int r = n * 16 + l15;
    bias_n[n] = rffb[h * 48 + r];
    #pragma unroll
    for (int ks = 0; ks < 2; ++ks)
      wf[n][ks] = *(const s16x8*)(WrT + (size_t)(h * 48 + r) * 64 + ks * 32 + lg * 8);
  }

  for (int c = half * 16 + w; c < half * 16 + 16; c += 8) {
    const int l0 = c * 64;
    s16x8 qf[4][2];
    #pragma unroll
    for (int m = 0; m < 4; ++m) {
      size_t ro = (size_t)((l0 + m * 16 + l15) * 16 + b) * 1536 + h * 64;
      #pragma unroll
      for (int ks = 0; ks < 2; ++ks)
        qf[m][ks] = *(const s16x8*)(qkv + ro + ks * 32 + lg * 8);
    }
    f32x4 p[4][3];
    #pragma unroll
    for (int m = 0; m < 4; ++m)
      #pragma unroll
      for (int n = 0; n < 3; ++n) {
        p[m][n] = fz + bias_n[n];
        #pragma unroll
        for (int ks = 0; ks < 2; ++ks)
          p[m][n] = __builtin_amdgcn_mfma_f32_16x16x32_bf16(qf[m][ks], wf[n][ks], p[m][n], 0, 0, 0);
      }
    #pragma unroll
    for (int m = 0; m < 4; ++m)
      #pragma unroll
      for (int n = 0; n < 3; ++n)
        #pragma unroll
        for (int q = 0; q < 4; ++q) {
          float pv = p[m][n][q];
          float ph = (pv > 0.f ? pv + 1.000001f : __expf(pv) + 1e-6f) * ISR;
          phiQ[w][m * 16 + lg * 4 + q][n * 16 + l15] = f2bits(ph);
        }
    s16x8 af[4][2], bv8[5][2];
    #pragma unroll
    for (int m = 0; m < 4; ++m)
      #pragma unroll
      for (int ks = 0; ks < 2; ++ks)
        af[m][ks] = *(const s16x8*)&phiQ[w][m * 16 + l15][ks * 32 + lg * 8];
    #pragma unroll
    for (int n5 = 0; n5 < 5; ++n5)
      #pragma unroll
      for (int ks = 0; ks < 2; ++ks)
        bv8[n5][ks] = *(const s16x8*)&KVT[n5 * 16 + l15][ks * 32 + lg * 8];
    f32x4 o[4][5];
    #pragma unroll
    for (int m = 0; m < 4; ++m)
      #pragma unroll
      for (int n5 = 0; n5 < 5; ++n5) {
        o[m][n5] = fz;
        #pragma unroll
        for (int ks = 0; ks < 2; ++ks)
          o[m][n5] = __builtin_amdgcn_mfma_f32_16x16x32_bf16(af[m][ks], bv8[n5][ks], o[m][n5], 0, 0, 0);
      }
    #pragma unroll
    for (int m = 0; m < 4; ++m)
      #pragma unroll
      for (int q = 0; q < 4; ++q) {
        float den = __shfl(o[m][4][q], lane & 48);
        float inv = 1.f / (den + 1e-6f);
        int gl = l0 + m * 16 + lg * 4 + q;
        size_t ob = (size_t)(gl * 16 + b) * 512 + h * 64;
        #pragma unroll
        for (int n = 0; n < 4; ++n)
          attn[ob + n * 16 + l15] = f2bits(o[m][n][q] * inv);
      }
  }
}

// ---------------- host ----------------
extern "C" void kernel_launch(void* const* d_in, const int* in_sizes, int n_in,
                              void* d_out, int out_size, void* d_ws, size_t ws_size,
                              hipStream_t stream) {
  (void)in_sizes; (void)n_in; (void)out_size; (void)ws_size;
  const float* x = (const float*)d_in[0];
  const float* Wq = (const float*)d_in[29];
  const float* Wk = (const float*)d_in[30];
  const float* Wv = (const float*)d_in[31];
  const float* bv = (const float*)d_in[32];
  const float* Wo = (const float*)d_in[33];
  const float* bo = (const float*)d_in[34];
  const float* wtq = (const float*)d_in[35];
  const float* wtk = (const float*)d_in[36];
  const float* rffW = (const float*)d_in[37];
  const float* rffb = (const float*)d_in[38];
  const float* fc1W = (const float*)d_in[39];
  const float* fc1b = (const float*)d_in[40];
  const float* fc2W = (const float*)d_in[41];
  const float* fc2b = (const float*)d_in[42];

  char* cur = (char*)d_ws;
  auto alloc = [&](size_t bytes) -> char* {
    char* r = cur;
    cur += (bytes + 255) & ~(size_t)255;
    return r;
  };
  float* c_qkv = (float*)alloc(1536 * 4);
  float* c1 = (float*)alloc(2048 * 4);
  float* c2 = (float*)alloc(512 * 4);
  float* dotqkv = (float*)alloc(1536 * 4);
  float* dot1   = (float*)alloc(2048 * 4);
  float* KVg   = (float*)alloc((size_t)256 * 3072 * 4);   // [half*128+bh][3072]
  float* Ksumg = (float*)alloc((size_t)256 * 48 * 4);
  unsigned short* AqkvT = (unsigned short*)alloc((size_t)1536 * 512 * 2);
  unsigned short* WoT   = (unsigned short*)alloc((size_t)512 * 512 * 2);
  unsigned short* A1T   = (unsigned short*)alloc((size_t)2048 * 512 * 2);
  unsigned short* A2T   = (unsigned short*)alloc((size_t)512 * 2048 * 2);
  unsigned short* WrT   = (unsigned short*)alloc((size_t)8 * 48 * 64 * 2);
  // big buffers (qkv and vT MUST be adjacent: g overlays both exactly)
  unsigned short* qkv   = (unsigned short*)alloc((size_t)NR * 1536 * 2);  // 96 MiB
  unsigned short* vT    = (unsigned short*)alloc((size_t)NR * 512 * 2);   // 32 MiB: vT then attn-out
  unsigned short* xb    = (unsigned short*)alloc((size_t)NR * 512 * 2);   // 32 MiB: bf16(x), lives to wo
  unsigned short* xrb   = (unsigned short*)alloc((size_t)NR * 512 * 2);   // 32 MiB
  unsigned short* attnO = vT;          // attn output reuses vT (dead after attn_A)
  unsigned short* g = qkv;             // fc1-out [NR][2048] bf16 = 128 MiB over qkv+vT (both dead)

  hipMemsetAsync(dotqkv, 0, 1536 * 4, stream);
  hipMemsetAsync(dot1, 0, 2048 * 4, stream);

  FoldArgs fa;
  fa.Wq = Wq; fa.Wk = Wk; fa.Wv = Wv; fa.Wo = Wo; fa.fc1W = fc1W; fa.fc2W = fc2W; fa.rffW = rffW;
  fa.x = x;
  for (int k = 0; k < 7; ++k) {
    fa.g[k] = (const float*)d_in[1 + k * 4 + 0];
    fa.b[k] = (const float*)d_in[1 + k * 4 + 1];
    fa.m[k] = (const float*)d_in[1 + k * 4 + 2];
    fa.v[k] = (const float*)d_in[1 + k * 4 + 3];
  }
  fa.dotqkv = dotqkv; fa.dot1 = dot1;
  fa.AqkvT = AqkvT; fa.WoT = WoT; fa.A1T = A1T; fa.A2T = A2T; fa.WrT = WrT;
  fa.xb = xb;
  fold_all<<<776 + 16384, 256, 0, stream>>>(fa);

  BiasArgs ba;
  ba.dotqkv = dotqkv; ba.dot1 = dot1; ba.bv = bv; ba.fc1b = fc1b; ba.fc2b = fc2b;
  for (int k = 0; k < 7; ++k) {
    ba.g[k] = (const float*)d_in[1 + k * 4 + 0];
    ba.b[k] = (const float*)d_in[1 + k * 4 + 1];
    ba.m[k] = (const float*)d_in[1 + k * 4 + 2];
    ba.v[k] = (const float*)d_in[1 + k * 4 + 3];
  }
  ba.c_qkv = c_qkv; ba.c1 = c1; ba.c2 = c2;
  bias_fin<<<8, 256, 0, stream>>>(ba);

  gemm_bf16<0><<<dim3(256, 12), 256, 0, stream>>>(xb, AqkvT, 512, 1536, c_qkv, nullptr, nullptr, qkv);
  scan_tr<<<1280, 1024, 0, stream>>>(qkv, wtq, wtk, vT);
  attn_A<<<dim3(128, 2), 512, 0, stream>>>(qkv, vT, WrT, rffb, KVg, Ksumg);
  attn_B<<<dim3(128, 2), 512, 0, stream>>>(qkv, WrT, rffb, KVg, Ksumg, attnO);
  gemm_bf16<1><<<dim3(256, 4), 256, 0, stream>>>(attnO, WoT, 512, 512, bo, xb, nullptr, xrb);
  gemm_bf16<2><<<dim3(256, 16), 256, 0, stream>>>(xrb, A1T, 512, 2048, c1, nullptr, nullptr, g);
  gemm_bf16<3><<<dim3(256, 4), 256, 0, stream>>>(g, A2T, 2048, 512, c2, xrb, (float*)d_out, nullptr);
}